// Round 15
// baseline (356.529 us; speedup 1.0000x reference)
//
#include <hip/hip_runtime.h>
#include <math.h>

#define B_ 4
#define T_ 2048
#define C_ 1024
#define NH_ 16
#define NKV_ 8
#define HD_ 64
#define KACT_ 8
#define VG_ 32
#define EPS_ 1e-6f
#define LOG2E_ 1.44269504088896340736f

typedef __attribute__((ext_vector_type(8))) short bf16x8;
typedef __attribute__((ext_vector_type(4))) float f32x4;
typedef __attribute__((ext_vector_type(4))) unsigned short u16x4;
typedef unsigned short u16;
typedef unsigned int u32;

__device__ inline u16 f2bf(float f) {
    u32 u = __float_as_uint(f);
    u += 0x7fffu + ((u >> 16) & 1u);   // RNE (finite data)
    return (u16)(u >> 16);
}

__device__ inline float fast_exp2(float x) {   // bare v_exp_f32 (D = 2^S0), no libm guards
    float r;
    asm("v_exp_f32 %0, %1" : "=v"(r) : "v"(x));
    return r;
}

__device__ inline void gload_lds16(const void* g, void* s) {
    __builtin_amdgcn_global_load_lds((const __attribute__((address_space(1))) void*)g,
                                     (__attribute__((address_space(3))) void*)s, 16, 0, 0);
}

// ===================== fused weight casts: Wq|Wk|Wv -> wqkv, Wo -> wo =====================
__global__ __launch_bounds__(256) void cast_weights_kernel(
    const float* __restrict__ Wq, const float* __restrict__ Wk,
    const float* __restrict__ Wv, const float* __restrict__ Wo,
    u16* __restrict__ wqkv, u16* __restrict__ wo)
{
    int i = blockIdx.x * 256 + threadIdx.x;    // 786432 float4 chunks total
    const float* src; u16* dst; int j;
    if (i < 262144)      { src = Wq; dst = wqkv;           j = i; }
    else if (i < 393216) { src = Wk; dst = wqkv + 1048576; j = i - 262144; }
    else if (i < 524288) { src = Wv; dst = wqkv + 1572864; j = i - 393216; }
    else                 { src = Wo; dst = wo;             j = i - 524288; }
    float4 v = ((const float4*)src)[j];
    u16x4 o = { f2bf(v.x), f2bf(v.y), f2bf(v.z), f2bf(v.w) };
    ((u16x4*)dst)[j] = o;
}

// ===================== bf16 NT-GEMM via MFMA (R2-proven, 2-barrier) =====================
// Out = A(MxK) * W(NxK)^T. 128x128 tile, BK=32, 4 waves (2x2), 64x64/wave.
// MODE 0: plain f32 Out. MODE 1: fused QKV epilogue (q f32 / k f32 / v bf16+gate*ve).
template<int MODE>
__global__ __launch_bounds__(256) void gemm_bf16_nt(
    const u16* __restrict__ A, const u16* __restrict__ W,
    float* __restrict__ Out, int M, int N, int K,
    float* __restrict__ q_out, float* __restrict__ k_out, u16* __restrict__ v_out,
    const float* __restrict__ gate, const float* __restrict__ ve)
{
    __shared__ __align__(16) u16 As[128 * 32];
    __shared__ __align__(16) u16 Ws[128 * 32];
    const int tid = threadIdx.x;
    const int lane = tid & 63;
    const int w = tid >> 6;
    const int bm = blockIdx.y * 128;
    const int bn = blockIdx.x * 128;
    const int wm = (w >> 1) * 64;
    const int wn = (w & 1) * 64;
    const int lr = lane & 15, lg = lane >> 4;

    f32x4 acc[4][4];
    #pragma unroll
    for (int mi = 0; mi < 4; ++mi)
        #pragma unroll
        for (int ni = 0; ni < 4; ++ni) acc[mi][ni] = f32x4{0.f, 0.f, 0.f, 0.f};

    for (int k0 = 0; k0 < K; k0 += 32) {
        __syncthreads();
        #pragma unroll
        for (int i = 0; i < 2; ++i) {
            int c = w * 128 + i * 64 + lane;      // 0..511, 16B chunks
            int row = c >> 2, kb8 = c & 3;
            gload_lds16(A + (size_t)(bm + row) * K + k0 + kb8 * 8, (char*)As + (size_t)c * 16);
            gload_lds16(W + (size_t)(bn + row) * K + k0 + kb8 * 8, (char*)Ws + (size_t)c * 16);
        }
        __syncthreads();   // drains vmcnt(0) + barrier
        bf16x8 af[4], bfr[4];
        #pragma unroll
        for (int mi = 0; mi < 4; ++mi)
            af[mi] = *(const bf16x8*)&As[(wm + mi * 16 + lr) * 32 + lg * 8];
        #pragma unroll
        for (int ni = 0; ni < 4; ++ni)
            bfr[ni] = *(const bf16x8*)&Ws[(wn + ni * 16 + lr) * 32 + lg * 8];
        __builtin_amdgcn_s_setprio(1);
        #pragma unroll
        for (int mi = 0; mi < 4; ++mi)
            #pragma unroll
            for (int ni = 0; ni < 4; ++ni)
                acc[mi][ni] = __builtin_amdgcn_mfma_f32_16x16x32_bf16(af[mi], bfr[ni], acc[mi][ni], 0, 0, 0);
        __builtin_amdgcn_s_setprio(0);
    }

    #pragma unroll
    for (int mi = 0; mi < 4; ++mi)
        #pragma unroll
        for (int ni = 0; ni < 4; ++ni)
            #pragma unroll
            for (int r = 0; r < 4; ++r) {
                const int row = bm + wm + mi * 16 + lg * 4 + r;
                const int col = bn + wn + ni * 16 + lr;
                const float val = acc[mi][ni][r];
                if (MODE == 0) {
                    Out[(size_t)row * N + col] = val;
                } else {
                    if (col < 1024) {
                        q_out[(size_t)row * 1024 + col] = val;
                    } else if (col < 1536) {
                        k_out[(size_t)row * 512 + (col - 1024)] = val;
                    } else {
                        const int cc = col - 1536;
                        v_out[(size_t)row * 512 + cc] =
                            f2bf(val + gate[row * NKV_ + (cc >> 6)] * ve[(size_t)row * 512 + cc]);
                    }
                }
            }
}

// ===================== Router + top-8 mask + gate + fused x->bf16 cast (R12-proven) ====
__global__ __launch_bounds__(64) void logits_mask_gate_kernel(
    const float* __restrict__ x, const float* __restrict__ Wr,
    const float* __restrict__ Wg, float* __restrict__ hm, float* __restrict__ gate,
    u16* __restrict__ xb)
{
    const int token = blockIdx.x;
    const int lane = threadIdx.x;
    const float* xr = x + (size_t)token * C_;
    __shared__ float lg[NH_];
    __shared__ float thr_s;
    float part[NH_];
    #pragma unroll
    for (int h = 0; h < NH_; ++h) part[h] = 0.f;
    for (int c = lane; c < C_; c += 64) {
        float xv = xr[c];
        xb[(size_t)token * C_ + c] = f2bf(xv);   // fused cast
        #pragma unroll
        for (int h = 0; h < NH_; ++h) part[h] = fmaf(xv, Wr[h * C_ + c], part[h]);
    }
    #pragma unroll
    for (int h = 0; h < NH_; ++h) {
        float s = part[h];
        #pragma unroll
        for (int off = 32; off; off >>= 1) s += __shfl_xor(s, off);
        if (lane == 0) lg[h] = s;
    }
    __syncthreads();
    if (lane == 0) {
        unsigned used = 0;
        float last = 0.f;
        for (int p = 0; p < KACT_; ++p) {
            float bv = -3.4e38f; int bi = 0;
            for (int i = 0; i < NH_; ++i)
                if (!(used & (1u << i)) && lg[i] > bv) { bv = lg[i]; bi = i; }
            used |= 1u << bi;
            last = bv;
        }
        thr_s = last;
    }
    __syncthreads();
    if (lane < NH_) hm[(size_t)token * NH_ + lane] = (lg[lane] >= thr_s) ? 1.f : 0.f;
    if (lane < NKV_) {
        float s = 0.f;
        #pragma unroll
        for (int g = 0; g < VG_; ++g) s = fmaf(xr[g], Wg[lane * VG_ + g], s);
        gate[(size_t)token * NKV_ + lane] = 2.f / (1.f + __expf(-s));
    }
}

// ===================== rotary + rms-norm, 16-vec/block, HEAD-major out (R7-proven) ====
__global__ __launch_bounds__(256) void rope_rms_kernel(
    const float* __restrict__ src, int src_stride, u16* __restrict__ dst,
    const float* __restrict__ cosT, const float* __restrict__ sinT,
    int hshift, float scale)
{
    const int tid = threadIdx.x;
    const int vec = blockIdx.x * 16 + (tid >> 4);   // = m*heads + h
    const int idx = tid & 15;
    const int heads = 1 << hshift;
    const int m = vec >> hshift;
    const int hh = vec & (heads - 1);
    const int t = m & (T_ - 1);
    const int bb = m >> 11;
    const float4 v4 = *(const float4*)(src + (size_t)m * src_stride + hh * 64 + idx * 4);
    const float4 c4 = *(const float4*)(cosT + t * 32 + (idx & 7) * 4);
    const float4 s4 = *(const float4*)(sinT + t * 32 + (idx & 7) * 4);
    const float p0 = __shfl_xor(v4.x, 8);
    const float p1 = __shfl_xor(v4.y, 8);
    const float p2 = __shfl_xor(v4.z, 8);
    const float p3 = __shfl_xor(v4.w, 8);
    float r0, r1, r2, r3;
    if (idx < 8) {
        r0 = fmaf(v4.x, c4.x, p0 * s4.x); r1 = fmaf(v4.y, c4.y, p1 * s4.y);
        r2 = fmaf(v4.z, c4.z, p2 * s4.z); r3 = fmaf(v4.w, c4.w, p3 * s4.w);
    } else {
        r0 = fmaf(v4.x, c4.x, -p0 * s4.x); r1 = fmaf(v4.y, c4.y, -p1 * s4.y);
        r2 = fmaf(v4.z, c4.z, -p2 * s4.z); r3 = fmaf(v4.w, c4.w, -p3 * s4.w);
    }
    float ss = fmaf(r0, r0, fmaf(r1, r1, fmaf(r2, r2, r3 * r3)));
    ss += __shfl_xor(ss, 1);
    ss += __shfl_xor(ss, 2);
    ss += __shfl_xor(ss, 4);
    ss += __shfl_xor(ss, 8);
    const float sc = rsqrtf(ss * (1.0f / HD_) + EPS_) * scale;
    u16x4 o = { f2bf(r0 * sc), f2bf(r1 * sc), f2bf(r2 * sc), f2bf(r3 * sc) };
    *(u16x4*)(dst + ((size_t)(bb * heads + hh) * T_ + t) * HD_ + idx * 4) = o;
}

// ===================== vb [m][kv][d] -> vbT [b][kv][d][t] (R2 verbatim) =====================
__global__ __launch_bounds__(256) void transpose_v_kernel(
    const u16* __restrict__ vb, u16* __restrict__ vt)
{
    __shared__ __align__(16) u16 Ls[64 * 64];
    const int bid = blockIdx.x;
    const int tt = bid & 31;
    const int kv = (bid >> 5) & 7;
    const int b = bid >> 8;
    const int tid = threadIdx.x;
    const int t0 = tt * 64;
    #pragma unroll
    for (int it = 0; it < 2; ++it) {
        int c = tid + it * 256;
        int tl = c >> 3, dg = c & 7;
        bf16x8 u = *(const bf16x8*)(vb + (((size_t)(b * T_) + t0 + tl) * NKV_ + kv) * HD_ + dg * 8);
        *(bf16x8*)((char*)Ls + ((tl * 128 + dg * 16) ^ ((tl & 7) << 4))) = u;
    }
    __syncthreads();
    #pragma unroll
    for (int it = 0; it < 2; ++it) {
        int c = tid + it * 256;
        int d = c >> 3, tg = c & 7;
        u16 vals[8];
        #pragma unroll
        for (int j = 0; j < 8; ++j) {
            int tl = tg * 8 + j;
            vals[j] = *(const u16*)((char*)Ls + ((tl * 128 + d * 2) ^ ((tl & 7) << 4)));
        }
        *(bf16x8*)(vt + (((size_t)(b * NKV_) + kv) * HD_ + d) * (size_t)T_ + t0 + tg * 8) = *(bf16x8*)vals;
    }
}

// ===================== MFMA flash attention v5: paired KV-tiles (2 per barrier-pair) ===
// Per-tile math is R12 VERBATIM (elementwise mask — branchy diag-only form miscompiles,
// convicted R9/R10; same tile order -> bit-identical f32 sequence). Two 64-key sub-tiles
// double-buffered in LDS; barriers halved. LDS staging REQUIRED (R13: L2-direct = 2.4x
// regression). block = (b, h, 64 q rows); wave w owns rows w*16..w*16+15.
// Swapped QK^T: St = mfma(A=K, B=Q) -> col(lane&15)=q, row=key. Softmax lane-local.
__global__ __launch_bounds__(256) void attn_mfma_kernel(
    const u16* __restrict__ qb, const u16* __restrict__ kb,
    const u16* __restrict__ vbT, const float* __restrict__ hm,
    u16* __restrict__ yb)
{
    __shared__ __align__(16) u16 Ks[2][64 * 72];
    __shared__ __align__(16) u16 Vt[2][64 * 72];
    __shared__ __align__(16) u16 Ps[4 * 16 * 72];
    const int bid = blockIdx.x;
    const int qt = 31 - (bid & 31);            // reversed: longest blocks first
    const int h = (bid >> 5) & 15;
    const int b = bid >> 9;
    const int kv = h >> 1;
    const int tid = threadIdx.x;
    const int lane = tid & 63;
    const int w = tid >> 6;
    const int lr = lane & 15;
    const int lg = lane >> 4;

    bf16x8 qf[2];
    {
        const u16* src = qb + ((size_t)(b * NH_ + h) * T_ + qt * 64 + w * 16 + lr) * HD_ + lg * 8;
        qf[0] = *(const bf16x8*)(src);
        qf[1] = *(const bf16x8*)(src + 32);
    }
    f32x4 yacc[4];
    #pragma unroll
    for (int dt = 0; dt < 4; ++dt) yacc[dt] = f32x4{0.f, 0.f, 0.f, 0.f};
    float m = -1e30f, l = 0.f;

    const u16* kbase = kb + (size_t)(b * NKV_ + kv) * T_ * HD_;            // head-major [t][64]
    const u16* vbase = vbT + ((size_t)(b * NKV_) + kv) * (size_t)HD_ * T_; // [d][t]
    u16* Pw = Ps + w * 16 * 72;
    const int qrow_g = qt * 64 + w * 16 + lr;

    const int a0 = tid >> 3,          g0 = tid & 7;
    const int a1 = (tid + 256) >> 3,  g1 = tid & 7;
    bf16x8 kA0, kA1, vA0, vA1, kB0, kB1, vB0, vB1;
    auto LOADT = [&](int kt, bf16x8& r0, bf16x8& r1, bf16x8& r2, bf16x8& r3) {
        r0 = *(const bf16x8*)(kbase + (size_t)(kt * 64 + a0) * HD_ + g0 * 8);
        r2 = *(const bf16x8*)(vbase + (size_t)a0 * T_ + kt * 64 + g0 * 8);
        r1 = *(const bf16x8*)(kbase + (size_t)(kt * 64 + a1) * HD_ + g1 * 8);
        r3 = *(const bf16x8*)(vbase + (size_t)a1 * T_ + kt * 64 + g1 * 8);
    };
    auto WRITET = [&](int s, bf16x8 r0, bf16x8 r1, bf16x8 r2, bf16x8 r3) {
        *(bf16x8*)&Ks[s][a0 * 72 + g0 * 8] = r0;
        *(bf16x8*)&Vt[s][a0 * 72 + g0 * 8] = r2;
        *(bf16x8*)&Ks[s][a1 * 72 + g1 * 8] = r1;
        *(bf16x8*)&Vt[s][a1 * 72 + g1 * 8] = r3;
    };
    // per-tile body: R12 VERBATIM with kt->kk, buffers parameterized
    auto PROCESS = [&](int kk, const u16* KsB, const u16* VtB) {
        const bool diag = (kk == qt);
        const int mtmax = diag ? w : 3;
        f32x4 st[4];
        #pragma unroll
        for (int mt = 0; mt < 4; ++mt) st[mt] = f32x4{0.f, 0.f, 0.f, 0.f};
        __builtin_amdgcn_s_setprio(1);
        #pragma unroll
        for (int mt = 0; mt < 4; ++mt) {
            if (mt <= mtmax) {
                bf16x8 kf0 = *(const bf16x8*)&KsB[(mt * 16 + lr) * 72 + lg * 8];
                bf16x8 kf1 = *(const bf16x8*)&KsB[(mt * 16 + lr) * 72 + lg * 8 + 32];
                st[mt] = __builtin_amdgcn_mfma_f32_16x16x32_bf16(kf0, qf[0], st[mt], 0, 0, 0);
                st[mt] = __builtin_amdgcn_mfma_f32_16x16x32_bf16(kf1, qf[1], st[mt], 0, 0, 0);
            }
        }
        __builtin_amdgcn_s_setprio(0);
        float smax = -1e30f;
        #pragma unroll
        for (int mt = 0; mt < 4; ++mt) {
            #pragma unroll
            for (int r = 0; r < 4; ++r) {
                int keyg = kk * 64 + mt * 16 + lg * 4 + r;
                float s = (mt <= mtmax && keyg <= qrow_g) ? st[mt][r] : -1e30f;
                st[mt][r] = s;
                smax = fmaxf(smax, s);
            }
        }
        smax = fmaxf(smax, __shfl_xor(smax, 16));
        smax = fmaxf(smax, __shfl_xor(smax, 32));
        if (!__all(smax <= m + 8.f)) {         // defer-max: P bounded by 2^8, bf16-safe
            const float mnew = fmaxf(m, smax);
            const float corr = fast_exp2(m - mnew);
            l *= corr;
            float cr[4];
            #pragma unroll
            for (int r = 0; r < 4; ++r) cr[r] = __shfl(corr, lg * 4 + r);
            #pragma unroll
            for (int dt = 0; dt < 4; ++dt)
                #pragma unroll
                for (int r = 0; r < 4; ++r) yacc[dt][r] *= cr[r];
            m = mnew;
        }
        float psum = 0.f;
        #pragma unroll
        for (int mt = 0; mt < 4; ++mt) {
            float p0 = fast_exp2(st[mt][0] - m);
            float p1 = fast_exp2(st[mt][1] - m);
            float p2 = fast_exp2(st[mt][2] - m);
            float p3 = fast_exp2(st[mt][3] - m);
            psum += (p0 + p1) + (p2 + p3);
            u16x4 pk = { f2bf(p0), f2bf(p1), f2bf(p2), f2bf(p3) };
            *(u16x4*)&Pw[lr * 72 + mt * 16 + lg * 4] = pk;
        }
        psum += __shfl_xor(psum, 16);
        psum += __shfl_xor(psum, 32);
        l += psum;
        const int kimax = diag ? (w >> 1) : 1;
        __builtin_amdgcn_s_setprio(1);
        #pragma unroll
        for (int ki = 0; ki < 2; ++ki) {
            if (ki <= kimax) {
                bf16x8 pf = *(const bf16x8*)&Pw[lr * 72 + ki * 32 + lg * 8];
                #pragma unroll
                for (int dt = 0; dt < 4; ++dt) {
                    bf16x8 vf = *(const bf16x8*)&VtB[(dt * 16 + lr) * 72 + ki * 32 + lg * 8];
                    yacc[dt] = __builtin_amdgcn_mfma_f32_16x16x32_bf16(pf, vf, yacc[dt], 0, 0, 0);
                }
            }
        }
        __builtin_amdgcn_s_setprio(0);
    };

    LOADT(0, kA0, kA1, vA0, vA1);
    LOADT(qt > 0 ? 1 : 0, kB0, kB1, vB0, vB1);
    WRITET(0, kA0, kA1, vA0, vA1);
    WRITET(1, kB0, kB1, vB0, vB1);
    for (int kt2 = 0; kt2 <= qt; kt2 += 2) {
        __syncthreads();                       // pair (kt2, kt2+1) visible in LDS
        const bool pre = (kt2 + 2 <= qt);
        if (pre) {
            LOADT(kt2 + 2, kA0, kA1, vA0, vA1);
            LOADT(kt2 + 3 <= qt ? kt2 + 3 : qt, kB0, kB1, vB0, vB1);
        }
        PROCESS(kt2, &Ks[0][0], &Vt[0][0]);
        if (kt2 + 1 <= qt) PROCESS(kt2 + 1, &Ks[1][0], &Vt[1][0]);
        __syncthreads();                       // all waves done with this pair
        if (pre) {
            WRITET(0, kA0, kA1, vA0, vA1);
            WRITET(1, kB0, kB1, vB0, vB1);
        }
    }
    const float linv = 1.f / l;
    #pragma unroll
    for (int r = 0; r < 4; ++r) {
        const float lrv = __shfl(linv, lg * 4 + r);
        const int t = qt * 64 + w * 16 + lg * 4 + r;
        const float hmv = hm[((size_t)(b * T_) + t) * NH_ + h];
        const float sc = lrv * hmv;
        #pragma unroll
        for (int dt = 0; dt < 4; ++dt)
            yb[(((size_t)(b * T_) + t) * NH_ + h) * HD_ + dt * 16 + lr] = f2bf(yacc[dt][r] * sc);
    }
}

extern "C" void kernel_launch(void* const* d_in, const int* in_sizes, int n_in,
                              void* d_out, int out_size, void* d_ws, size_t ws_size,
                              hipStream_t stream) {
    const float* x    = (const float*)d_in[0];
    const float* ve   = (const float*)d_in[1];
    const float* cosT = (const float*)d_in[2];
    const float* sinT = (const float*)d_in[3];
    const float* Wq   = (const float*)d_in[4];
    const float* Wk   = (const float*)d_in[5];
    const float* Wv   = (const float*)d_in[6];
    const float* Wo   = (const float*)d_in[7];
    const float* Wr   = (const float*)d_in[8];
    const float* Wg   = (const float*)d_in[9];
    float* out = (float*)d_out;
    float* hm  = out + (size_t)B_ * T_ * C_;

    const int M = B_ * T_;  // 8192
    float* ws = (float*)d_ws;
    float* qf32  = ws;                  // 8388608 f   [after rope_q: yb bf16]
    float* kf32  = qf32 + 8388608;      // 4194304 f   [after rope_k: vbT bf16]
    float* xbr   = kf32 + 4194304;      // 4194304 f (bf16 x) [after QKV gemm: qb bf16]
    float* wqkvr = xbr + 4194304;       // 1048576 f (bf16 Wqkv)
    float* wor   = wqkvr + 1048576;     // 524288 f  (bf16 Wo)
    float* gate  = wor + 524288;        // 65536 f
    float* vbr   = gate + 65536;        // 2097152 f (bf16 v, token-major)
    float* kbr   = vbr + 2097152;       // 2097152 f (bf16 k roped, head-major)

    u16* xb    = (u16*)xbr;
    u16* Wqkvb = (u16*)wqkvr;
    u16* Wob   = (u16*)wor;
    u16* vb    = (u16*)vbr;
    u16* qb    = (u16*)xbr;    // overlays xb (dead after QKV GEMM), head-major
    u16* kb    = (u16*)kbr;    // head-major
    u16* vbT   = (u16*)kf32;   // overlays kf32 (dead after rope_k)
    u16* yb    = (u16*)qf32;   // overlays qf32 (dead after rope_q)

    // ---- weight casts ----
    cast_weights_kernel<<<3072, 256, 0, stream>>>(Wq, Wk, Wv, Wo, Wqkvb, Wob);
    // ---- router (R12 form; gate feeds the fused V epilogue; also emits xb) ----
    logits_mask_gate_kernel<<<M, 64, 0, stream>>>(x, Wr, Wg, hm, gate, xb);
    // ---- fused QKV projection ----
    gemm_bf16_nt<1><<<dim3(2048 / 128, M / 128), 256, 0, stream>>>(
        xb, Wqkvb, nullptr, M, 2048, C_, qf32, kf32, vb, gate, ve);
    // ---- rope+rms -> bf16 head-major (q folded with 1/sqrt(HD)*log2e for exp2 softmax) ----
    rope_rms_kernel<<<(M * NH_) / 16, 256, 0, stream>>>(qf32, 1024, qb, cosT, sinT, 4, 0.125f * LOG2E_);
    rope_rms_kernel<<<(M * NKV_) / 16, 256, 0, stream>>>(kf32, 512, kb, cosT, sinT, 3, 1.0f);
    // ---- V transpose ----
    transpose_v_kernel<<<B_ * NKV_ * (T_ / 64), 256, 0, stream>>>(vb, vbT);
    // ---- flash attention (paired KV-tiles) ----
    attn_mfma_kernel<<<B_ * NH_ * (T_ / 64), 256, 0, stream>>>(qb, kb, vbT, hm, yb);
    // ---- output projection ----
    gemm_bf16_nt<0><<<dim3(C_ / 128, M / 128), 256, 0, stream>>>(
        yb, Wob, out, M, C_, C_, nullptr, nullptr, nullptr, nullptr, nullptr);
}

// Round 16
// 315.770 us; speedup vs baseline: 1.1291x; 1.1291x over previous
//
#include <hip/hip_runtime.h>
#include <math.h>

#define B_ 4
#define T_ 2048
#define C_ 1024
#define NH_ 16
#define NKV_ 8
#define HD_ 64
#define KACT_ 8
#define VG_ 32
#define EPS_ 1e-6f
#define LOG2E_ 1.44269504088896340736f

typedef __attribute__((ext_vector_type(8))) short bf16x8;
typedef __attribute__((ext_vector_type(4))) float f32x4;
typedef __attribute__((ext_vector_type(4))) unsigned short u16x4;
typedef unsigned short u16;
typedef unsigned int u32;

__device__ inline u16 f2bf(float f) {
    u32 u = __float_as_uint(f);
    u += 0x7fffu + ((u >> 16) & 1u);   // RNE (finite data)
    return (u16)(u >> 16);
}

__device__ inline float fast_exp2(float x) {   // bare v_exp_f32 (D = 2^S0), no libm guards
    float r;
    asm("v_exp_f32 %0, %1" : "=v"(r) : "v"(x));
    return r;
}

__device__ inline void gload_lds16(const void* g, void* s) {
    __builtin_amdgcn_global_load_lds((const __attribute__((address_space(1))) void*)g,
                                     (__attribute__((address_space(3))) void*)s, 16, 0, 0);
}

__device__ inline void bar() {                 // raw barrier + compiler memory fence
    asm volatile("" ::: "memory");
    __builtin_amdgcn_s_barrier();
    asm volatile("" ::: "memory");
}

// st_16x32 swizzle (involution): byte ^= ((byte>>9)&1)<<5 within a 16KB [128][64]bf16 unit
__device__ inline int swz(int b) { return b ^ (((b >> 9) & 1) << 5); }

// ===================== fused weight casts: Wq|Wk|Wv -> wqkv, Wo -> wo =====================
__global__ __launch_bounds__(256) void cast_weights_kernel(
    const float* __restrict__ Wq, const float* __restrict__ Wk,
    const float* __restrict__ Wv, const float* __restrict__ Wo,
    u16* __restrict__ wqkv, u16* __restrict__ wo)
{
    int i = blockIdx.x * 256 + threadIdx.x;    // 786432 float4 chunks total
    const float* src; u16* dst; int j;
    if (i < 262144)      { src = Wq; dst = wqkv;           j = i; }
    else if (i < 393216) { src = Wk; dst = wqkv + 1048576; j = i - 262144; }
    else if (i < 524288) { src = Wv; dst = wqkv + 1572864; j = i - 393216; }
    else                 { src = Wo; dst = wo;             j = i - 524288; }
    float4 v = ((const float4*)src)[j];
    u16x4 o = { f2bf(v.x), f2bf(v.y), f2bf(v.z), f2bf(v.w) };
    ((u16x4*)dst)[j] = o;
}

// ===================== bf16 NT-GEMM: 256x128 tile, counted-vmcnt pipeline =====================
// Out = A(MxK) * W(NxK)^T. BK=64, 512 threads = 8 waves (2M x 4N), wave tile 128x32.
// A triple-buffered (stage kt+2), B double-buffered (stage kt+1): a buffer is NEVER
// written while readable -> race-free by construction. vmcnt(4) at K-tile entry keeps
// A(kt+1)'s 4 loads in flight (T4 counted vmcnt); vmcnt(0) only at the last K-tile.
// st_16x32 swizzle: linear gload_lds dest + pre-swizzled SOURCE chunk + swizzled read
// (same involution both sides, rule 21). K accumulation order identical to the R2 kernel
// (kt asc, kk asc) -> bit-identical outputs.
// MODE 0: plain f32 Out. MODE 1: fused QKV epilogue (q f32 / k f32 / v bf16+gate*ve).
template<int MODE>
__global__ __launch_bounds__(512) void gemm_bf16_256(
    const u16* __restrict__ A, const u16* __restrict__ W,
    float* __restrict__ Out, int M, int N, int K,
    float* __restrict__ q_out, float* __restrict__ k_out, u16* __restrict__ v_out,
    const float* __restrict__ gate, const float* __restrict__ ve)
{
    __shared__ __align__(16) u16 AL[3][2][128 * 64];   // 96 KB
    __shared__ __align__(16) u16 BL[2][128 * 64];      // 32 KB
    const int tid = threadIdx.x;
    const int lane = tid & 63;
    const int w = tid >> 6;
    const int bm = blockIdx.y * 256;
    const int bn = blockIdx.x * 128;
    const int wm = (w >> 2) * 128;     // A half = w>>2
    const int wn = (w & 3) * 32;
    const int ah = w >> 2;
    const int lr = lane & 15, lg = lane >> 4;
    const int NKT = K >> 6;            // 16

    f32x4 acc[8][2];
    #pragma unroll
    for (int mi = 0; mi < 8; ++mi)
        #pragma unroll
        for (int ni = 0; ni < 2; ++ni) acc[mi][ni] = f32x4{0.f, 0.f, 0.f, 0.f};

    // staging: thread t covers chunks {t, t+512} of each 16KB unit; source pre-swizzled
    auto stageA = [&](int kt) {        // both halves, 4 loads FIFO
        const int db = kt % 3;
        #pragma unroll
        for (int hf = 0; hf < 2; ++hf)
            #pragma unroll
            for (int ci = 0; ci < 2; ++ci) {
                int c = tid + ci * 512;
                int l = c ^ (((c >> 5) & 1) << 1);
                gload_lds16(A + (size_t)(bm + hf * 128 + (l >> 3)) * K + kt * 64 + (l & 7) * 8,
                            (char*)&AL[db][hf][0] + c * 16);
            }
    };
    auto stageB = [&](int kt) {        // 2 loads
        const int db = kt & 1;
        #pragma unroll
        for (int ci = 0; ci < 2; ++ci) {
            int c = tid + ci * 512;
            int l = c ^ (((c >> 5) & 1) << 1);
            gload_lds16(W + (size_t)(bn + (l >> 3)) * K + kt * 64 + (l & 7) * 8,
                        (char*)&BL[db][0] + c * 16);
        }
    };

    stageA(0);
    stageB(0);
    stageA(1);                          // FIFO: [A0(4), B0(2), A1(4)]

    for (int kt = 0; kt < NKT; ++kt) {
        const int ab = kt % 3, bb = kt & 1;
        if (kt == NKT - 1) asm volatile("s_waitcnt vmcnt(0)" ::: "memory");
        else               asm volatile("s_waitcnt vmcnt(4)" ::: "memory");
        bar();                          // all waves' loads for K-tile kt landed
        #pragma unroll
        for (int ph = 0; ph < 2; ++ph) {
            bf16x8 af[4][2], bfm[2][2];
            #pragma unroll
            for (int mi2 = 0; mi2 < 4; ++mi2) {
                const int row = (ph * 4 + mi2) * 16 + lr;
                #pragma unroll
                for (int kk = 0; kk < 2; ++kk)
                    af[mi2][kk] = *(const bf16x8*)((const char*)&AL[ab][ah][0] +
                                                   swz(row * 128 + kk * 64 + lg * 16));
            }
            #pragma unroll
            for (int ni = 0; ni < 2; ++ni) {
                const int row = wn + ni * 16 + lr;
                #pragma unroll
                for (int kk = 0; kk < 2; ++kk)
                    bfm[ni][kk] = *(const bf16x8*)((const char*)&BL[bb][0] +
                                                   swz(row * 128 + kk * 64 + lg * 16));
            }
            if (ph == 0) { if (kt + 1 < NKT) stageB(kt + 1); }
            else         { if (kt + 2 < NKT) stageA(kt + 2); }
            bar();
            __builtin_amdgcn_s_setprio(1);
            #pragma unroll
            for (int mi2 = 0; mi2 < 4; ++mi2)
                #pragma unroll
                for (int ni = 0; ni < 2; ++ni)
                    #pragma unroll
                    for (int kk = 0; kk < 2; ++kk)
                        acc[ph * 4 + mi2][ni] = __builtin_amdgcn_mfma_f32_16x16x32_bf16(
                            af[mi2][kk], bfm[ni][kk], acc[ph * 4 + mi2][ni], 0, 0, 0);
            __builtin_amdgcn_s_setprio(0);
            bar();
        }
    }

    #pragma unroll
    for (int mi = 0; mi < 8; ++mi)
        #pragma unroll
        for (int ni = 0; ni < 2; ++ni)
            #pragma unroll
            for (int r = 0; r < 4; ++r) {
                const int row = bm + wm + mi * 16 + lg * 4 + r;
                const int col = bn + wn + ni * 16 + lr;
                const float val = acc[mi][ni][r];
                if (MODE == 0) {
                    Out[(size_t)row * N + col] = val;
                } else {
                    if (col < 1024) {
                        q_out[(size_t)row * 1024 + col] = val;
                    } else if (col < 1536) {
                        k_out[(size_t)row * 512 + (col - 1024)] = val;
                    } else {
                        const int cc = col - 1536;
                        v_out[(size_t)row * 512 + cc] =
                            f2bf(val + gate[row * NKV_ + (cc >> 6)] * ve[(size_t)row * 512 + cc]);
                    }
                }
            }
}

// ===================== Router + top-8 mask + gate + fused x->bf16 cast (R12-proven) ====
__global__ __launch_bounds__(64) void logits_mask_gate_kernel(
    const float* __restrict__ x, const float* __restrict__ Wr,
    const float* __restrict__ Wg, float* __restrict__ hm, float* __restrict__ gate,
    u16* __restrict__ xb)
{
    const int token = blockIdx.x;
    const int lane = threadIdx.x;
    const float* xr = x + (size_t)token * C_;
    __shared__ float lg[NH_];
    __shared__ float thr_s;
    float part[NH_];
    #pragma unroll
    for (int h = 0; h < NH_; ++h) part[h] = 0.f;
    for (int c = lane; c < C_; c += 64) {
        float xv = xr[c];
        xb[(size_t)token * C_ + c] = f2bf(xv);   // fused cast
        #pragma unroll
        for (int h = 0; h < NH_; ++h) part[h] = fmaf(xv, Wr[h * C_ + c], part[h]);
    }
    #pragma unroll
    for (int h = 0; h < NH_; ++h) {
        float s = part[h];
        #pragma unroll
        for (int off = 32; off; off >>= 1) s += __shfl_xor(s, off);
        if (lane == 0) lg[h] = s;
    }
    __syncthreads();
    if (lane == 0) {
        unsigned used = 0;
        float last = 0.f;
        for (int p = 0; p < KACT_; ++p) {
            float bv = -3.4e38f; int bi = 0;
            for (int i = 0; i < NH_; ++i)
                if (!(used & (1u << i)) && lg[i] > bv) { bv = lg[i]; bi = i; }
            used |= 1u << bi;
            last = bv;
        }
        thr_s = last;
    }
    __syncthreads();
    if (lane < NH_) hm[(size_t)token * NH_ + lane] = (lg[lane] >= thr_s) ? 1.f : 0.f;
    if (lane < NKV_) {
        float s = 0.f;
        #pragma unroll
        for (int g = 0; g < VG_; ++g) s = fmaf(xr[g], Wg[lane * VG_ + g], s);
        gate[(size_t)token * NKV_ + lane] = 2.f / (1.f + __expf(-s));
    }
}

// ===================== rotary + rms-norm, 16-vec/block, HEAD-major out (R7-proven) ====
__global__ __launch_bounds__(256) void rope_rms_kernel(
    const float* __restrict__ src, int src_stride, u16* __restrict__ dst,
    const float* __restrict__ cosT, const float* __restrict__ sinT,
    int hshift, float scale)
{
    const int tid = threadIdx.x;
    const int vec = blockIdx.x * 16 + (tid >> 4);   // = m*heads + h
    const int idx = tid & 15;
    const int heads = 1 << hshift;
    const int m = vec >> hshift;
    const int hh = vec & (heads - 1);
    const int t = m & (T_ - 1);
    const int bb = m >> 11;
    const float4 v4 = *(const float4*)(src + (size_t)m * src_stride + hh * 64 + idx * 4);
    const float4 c4 = *(const float4*)(cosT + t * 32 + (idx & 7) * 4);
    const float4 s4 = *(const float4*)(sinT + t * 32 + (idx & 7) * 4);
    const float p0 = __shfl_xor(v4.x, 8);
    const float p1 = __shfl_xor(v4.y, 8);
    const float p2 = __shfl_xor(v4.z, 8);
    const float p3 = __shfl_xor(v4.w, 8);
    float r0, r1, r2, r3;
    if (idx < 8) {
        r0 = fmaf(v4.x, c4.x, p0 * s4.x); r1 = fmaf(v4.y, c4.y, p1 * s4.y);
        r2 = fmaf(v4.z, c4.z, p2 * s4.z); r3 = fmaf(v4.w, c4.w, p3 * s4.w);
    } else {
        r0 = fmaf(v4.x, c4.x, -p0 * s4.x); r1 = fmaf(v4.y, c4.y, -p1 * s4.y);
        r2 = fmaf(v4.z, c4.z, -p2 * s4.z); r3 = fmaf(v4.w, c4.w, -p3 * s4.w);
    }
    float ss = fmaf(r0, r0, fmaf(r1, r1, fmaf(r2, r2, r3 * r3)));
    ss += __shfl_xor(ss, 1);
    ss += __shfl_xor(ss, 2);
    ss += __shfl_xor(ss, 4);
    ss += __shfl_xor(ss, 8);
    const float sc = rsqrtf(ss * (1.0f / HD_) + EPS_) * scale;
    u16x4 o = { f2bf(r0 * sc), f2bf(r1 * sc), f2bf(r2 * sc), f2bf(r3 * sc) };
    *(u16x4*)(dst + ((size_t)(bb * heads + hh) * T_ + t) * HD_ + idx * 4) = o;
}

// ===================== vb [m][kv][d] -> vbT [b][kv][d][t] (R2 verbatim) =====================
__global__ __launch_bounds__(256) void transpose_v_kernel(
    const u16* __restrict__ vb, u16* __restrict__ vt)
{
    __shared__ __align__(16) u16 Ls[64 * 64];
    const int bid = blockIdx.x;
    const int tt = bid & 31;
    const int kv = (bid >> 5) & 7;
    const int b = bid >> 8;
    const int tid = threadIdx.x;
    const int t0 = tt * 64;
    #pragma unroll
    for (int it = 0; it < 2; ++it) {
        int c = tid + it * 256;
        int tl = c >> 3, dg = c & 7;
        bf16x8 u = *(const bf16x8*)(vb + (((size_t)(b * T_) + t0 + tl) * NKV_ + kv) * HD_ + dg * 8);
        *(bf16x8*)((char*)Ls + ((tl * 128 + dg * 16) ^ ((tl & 7) << 4))) = u;
    }
    __syncthreads();
    #pragma unroll
    for (int it = 0; it < 2; ++it) {
        int c = tid + it * 256;
        int d = c >> 3, tg = c & 7;
        u16 vals[8];
        #pragma unroll
        for (int j = 0; j < 8; ++j) {
            int tl = tg * 8 + j;
            vals[j] = *(const u16*)((char*)Ls + ((tl * 128 + d * 2) ^ ((tl & 7) << 4)));
        }
        *(bf16x8*)(vt + (((size_t)(b * NKV_) + kv) * HD_ + d) * (size_t)T_ + t0 + tg * 8) = *(bf16x8*)vals;
    }
}

// ===================== MFMA flash attention (R12 verbatim — 149us proven) =============
// Elementwise causal mask (PROVEN form — do NOT restructure; branchy diag-only form
// miscompiles, convicted R9/R10). Softmax in exp2 domain (q pre-scaled 0.125*log2e).
// LDS staging REQUIRED (R13: L2-direct = 2.4x regression). Paired tiles regress (R15:
// occupancy loss). block = (b, h, 64 q rows); wave w owns rows w*16..w*16+15.
__global__ __launch_bounds__(256) void attn_mfma_kernel(
    const u16* __restrict__ qb, const u16* __restrict__ kb,
    const u16* __restrict__ vbT, const float* __restrict__ hm,
    u16* __restrict__ yb)
{
    __shared__ __align__(16) u16 Ks[64 * 72];
    __shared__ __align__(16) u16 Vt[64 * 72];
    __shared__ __align__(16) u16 Ps[4 * 16 * 72];
    const int bid = blockIdx.x;
    const int qt = 31 - (bid & 31);            // reversed: longest blocks first
    const int h = (bid >> 5) & 15;
    const int b = bid >> 9;
    const int kv = h >> 1;
    const int tid = threadIdx.x;
    const int lane = tid & 63;
    const int w = tid >> 6;
    const int lr = lane & 15;
    const int lg = lane >> 4;

    bf16x8 qf[2];
    {
        const u16* src = qb + ((size_t)(b * NH_ + h) * T_ + qt * 64 + w * 16 + lr) * HD_ + lg * 8;
        qf[0] = *(const bf16x8*)(src);
        qf[1] = *(const bf16x8*)(src + 32);
    }
    f32x4 yacc[4];
    #pragma unroll
    for (int dt = 0; dt < 4; ++dt) yacc[dt] = f32x4{0.f, 0.f, 0.f, 0.f};
    float m = -1e30f, l = 0.f;

    const u16* kbase = kb + (size_t)(b * NKV_ + kv) * T_ * HD_;            // head-major [t][64]
    const u16* vbase = vbT + ((size_t)(b * NKV_) + kv) * (size_t)HD_ * T_; // [d][t]
    u16* Pw = Ps + w * 16 * 72;
    const int qrow_g = qt * 64 + w * 16 + lr;

    const int a0 = tid >> 3,          g0 = tid & 7;
    const int a1 = (tid + 256) >> 3,  g1 = tid & 7;
    bf16x8 kreg0, kreg1, vreg0, vreg1;
    auto LOADT = [&](int kt) {
        kreg0 = *(const bf16x8*)(kbase + (size_t)(kt * 64 + a0) * HD_ + g0 * 8);
        vreg0 = *(const bf16x8*)(vbase + (size_t)a0 * T_ + kt * 64 + g0 * 8);
        kreg1 = *(const bf16x8*)(kbase + (size_t)(kt * 64 + a1) * HD_ + g1 * 8);
        vreg1 = *(const bf16x8*)(vbase + (size_t)a1 * T_ + kt * 64 + g1 * 8);
    };
    auto WRITET = [&]() {
        *(bf16x8*)&Ks[a0 * 72 + g0 * 8] = kreg0;
        *(bf16x8*)&Vt[a0 * 72 + g0 * 8] = vreg0;
        *(bf16x8*)&Ks[a1 * 72 + g1 * 8] = kreg1;
        *(bf16x8*)&Vt[a1 * 72 + g1 * 8] = vreg1;
    };

    LOADT(0);
    WRITET();
    for (int kt = 0; kt <= qt; ++kt) {
        __syncthreads();                       // tile kt visible in LDS
        if (kt < qt) LOADT(kt + 1);            // prefetch next tile into regs
        const bool diag = (kt == qt);
        const int mtmax = diag ? w : 3;
        f32x4 st[4];
        #pragma unroll
        for (int mt = 0; mt < 4; ++mt) st[mt] = f32x4{0.f, 0.f, 0.f, 0.f};
        __builtin_amdgcn_s_setprio(1);
        #pragma unroll
        for (int mt = 0; mt < 4; ++mt) {
            if (mt <= mtmax) {
                bf16x8 kf0 = *(const bf16x8*)&Ks[(mt * 16 + lr) * 72 + lg * 8];
                bf16x8 kf1 = *(const bf16x8*)&Ks[(mt * 16 + lr) * 72 + lg * 8 + 32];
                st[mt] = __builtin_amdgcn_mfma_f32_16x16x32_bf16(kf0, qf[0], st[mt], 0, 0, 0);
                st[mt] = __builtin_amdgcn_mfma_f32_16x16x32_bf16(kf1, qf[1], st[mt], 0, 0, 0);
            }
        }
        __builtin_amdgcn_s_setprio(0);
        // mask + per-q max (elementwise PROVEN form; lane's q = lr; keys: kt*64+mt*16+lg*4+r)
        float smax = -1e30f;
        #pragma unroll
        for (int mt = 0; mt < 4; ++mt) {
            #pragma unroll
            for (int r = 0; r < 4; ++r) {
                int keyg = kt * 64 + mt * 16 + lg * 4 + r;
                float s = (mt <= mtmax && keyg <= qrow_g) ? st[mt][r] : -1e30f;
                st[mt][r] = s;
                smax = fmaxf(smax, s);
            }
        }
        smax = fmaxf(smax, __shfl_xor(smax, 16));
        smax = fmaxf(smax, __shfl_xor(smax, 32));
        if (!__all(smax <= m + 8.f)) {         // defer-max: P bounded by 2^8, bf16-safe
            const float mnew = fmaxf(m, smax);
            const float corr = fast_exp2(m - mnew);
            l *= corr;
            float cr[4];
            #pragma unroll
            for (int r = 0; r < 4; ++r) cr[r] = __shfl(corr, lg * 4 + r);
            #pragma unroll
            for (int dt = 0; dt < 4; ++dt)
                #pragma unroll
                for (int r = 0; r < 4; ++r) yacc[dt][r] *= cr[r];
            m = mnew;
        }
        float psum = 0.f;
        #pragma unroll
        for (int mt = 0; mt < 4; ++mt) {
            float p0 = fast_exp2(st[mt][0] - m);
            float p1 = fast_exp2(st[mt][1] - m);
            float p2 = fast_exp2(st[mt][2] - m);
            float p3 = fast_exp2(st[mt][3] - m);
            psum += (p0 + p1) + (p2 + p3);
            u16x4 pk = { f2bf(p0), f2bf(p1), f2bf(p2), f2bf(p3) };
            *(u16x4*)&Pw[lr * 72 + mt * 16 + lg * 4] = pk;   // P[q][s] row-major, stride 72
        }
        psum += __shfl_xor(psum, 16);
        psum += __shfl_xor(psum, 32);
        l += psum;
        // PV: Y[q][d] += P[q][s] * V[s][d]
        const int kimax = diag ? (w >> 1) : 1;
        __builtin_amdgcn_s_setprio(1);
        #pragma unroll
        for (int ki = 0; ki < 2; ++ki) {
            if (ki <= kimax) {
                bf16x8 pf = *(const bf16x8*)&Pw[lr * 72 + ki * 32 + lg * 8];
                #pragma unroll
                for (int dt = 0; dt < 4; ++dt) {
                    bf16x8 vf = *(const bf16x8*)&Vt[(dt * 16 + lr) * 72 + ki * 32 + lg * 8];
                    yacc[dt] = __builtin_amdgcn_mfma_f32_16x16x32_bf16(pf, vf, yacc[dt], 0, 0, 0);
                }
            }
        }
        __builtin_amdgcn_s_setprio(0);
        __syncthreads();                       // all waves done reading tile kt
        if (kt < qt) WRITET();                 // overwrite LDS with tile kt+1
    }
    const float linv = 1.f / l;
    #pragma unroll
    for (int r = 0; r < 4; ++r) {
        const float lrv = __shfl(linv, lg * 4 + r);
        const int t = qt * 64 + w * 16 + lg * 4 + r;
        const float hmv = hm[((size_t)(b * T_) + t) * NH_ + h];
        const float sc = lrv * hmv;
        #pragma unroll
        for (int dt = 0; dt < 4; ++dt)
            yb[(((size_t)(b * T_) + t) * NH_ + h) * HD_ + dt * 16 + lr] = f2bf(yacc[dt][r] * sc);
    }
}

extern "C" void kernel_launch(void* const* d_in, const int* in_sizes, int n_in,
                              void* d_out, int out_size, void* d_ws, size_t ws_size,
                              hipStream_t stream) {
    const float* x    = (const float*)d_in[0];
    const float* ve   = (const float*)d_in[1];
    const float* cosT = (const float*)d_in[2];
    const float* sinT = (const float*)d_in[3];
    const float* Wq   = (const float*)d_in[4];
    const float* Wk   = (const float*)d_in[5];
    const float* Wv   = (const float*)d_in[6];
    const float* Wo   = (const float*)d_in[7];
    const float* Wr   = (const float*)d_in[8];
    const float* Wg   = (const float*)d_in[9];
    float* out = (float*)d_out;
    float* hm  = out + (size_t)B_ * T_ * C_;

    const int M = B_ * T_;  // 8192
    float* ws = (float*)d_ws;
    float* qf32  = ws;                  // 8388608 f   [after rope_q: yb bf16]
    float* kf32  = qf32 + 8388608;      // 4194304 f   [after rope_k: vbT bf16]
    float* xbr   = kf32 + 4194304;      // 4194304 f (bf16 x) [after QKV gemm: qb bf16]
    float* wqkvr = xbr + 4194304;       // 1048576 f (bf16 Wqkv)
    float* wor   = wqkvr + 1048576;     // 524288 f  (bf16 Wo)
    float* gate  = wor + 524288;        // 65536 f
    float* vbr   = gate + 65536;        // 2097152 f (bf16 v, token-major)
    float* kbr   = vbr + 2097152;       // 2097152 f (bf16 k roped, head-major)

    u16* xb    = (u16*)xbr;
    u16* Wqkvb = (u16*)wqkvr;
    u16* Wob   = (u16*)wor;
    u16* vb    = (u16*)vbr;
    u16* qb    = (u16*)xbr;    // overlays xb (dead after QKV GEMM), head-major
    u16* kb    = (u16*)kbr;    // head-major
    u16* vbT   = (u16*)kf32;   // overlays kf32 (dead after rope_k)
    u16* yb    = (u16*)qf32;   // overlays qf32 (dead after rope_q)

    // ---- weight casts ----
    cast_weights_kernel<<<3072, 256, 0, stream>>>(Wq, Wk, Wv, Wo, Wqkvb, Wob);
    // ---- router (gate feeds the fused V epilogue; also emits xb) ----
    logits_mask_gate_kernel<<<M, 64, 0, stream>>>(x, Wr, Wg, hm, gate, xb);
    // ---- fused QKV projection (256x128 counted-vmcnt pipeline) ----
    gemm_bf16_256<1><<<dim3(2048 / 128, M / 256), 512, 0, stream>>>(
        xb, Wqkvb, nullptr, M, 2048, C_, qf32, kf32, vb, gate, ve);
    // ---- rope+rms -> bf16 head-major (q folded with 1/sqrt(HD)*log2e for exp2 softmax) ----
    rope_rms_kernel<<<(M * NH_) / 16, 256, 0, stream>>>(qf32, 1024, qb, cosT, sinT, 4, 0.125f * LOG2E_);
    rope_rms_kernel<<<(M * NKV_) / 16, 256, 0, stream>>>(kf32, 512, kb, cosT, sinT, 3, 1.0f);
    // ---- V transpose ----
    transpose_v_kernel<<<B_ * NKV_ * (T_ / 64), 256, 0, stream>>>(vb, vbT);
    // ---- flash attention (R12 verbatim) ----
    attn_mfma_kernel<<<B_ * NH_ * (T_ / 64), 256, 0, stream>>>(qb, kb, vbT, hm, yb);
    // ---- output projection (256x128 pipeline) ----
    gemm_bf16_256<0><<<dim3(C_ / 128, M / 256), 512, 0, stream>>>(
        yb, Wob, out, M, C_, C_, nullptr, nullptr, nullptr, nullptr, nullptr);
}

// Round 17
// 308.804 us; speedup vs baseline: 1.1545x; 1.0226x over previous
//
#include <hip/hip_runtime.h>
#include <math.h>

#define B_ 4
#define T_ 2048
#define C_ 1024
#define NH_ 16
#define NKV_ 8
#define HD_ 64
#define KACT_ 8
#define VG_ 32
#define EPS_ 1e-6f
#define LOG2E_ 1.44269504088896340736f

typedef __attribute__((ext_vector_type(8))) short bf16x8;
typedef __attribute__((ext_vector_type(4))) float f32x4;
typedef __attribute__((ext_vector_type(4))) unsigned short u16x4;
typedef unsigned short u16;
typedef unsigned int u32;

__device__ inline u16 f2bf(float f) {
    u32 u = __float_as_uint(f);
    u += 0x7fffu + ((u >> 16) & 1u);   // RNE (finite data)
    return (u16)(u >> 16);
}

__device__ inline float fast_exp2(float x) {   // bare v_exp_f32 (D = 2^S0), no libm guards
    float r;
    asm("v_exp_f32 %0, %1" : "=v"(r) : "v"(x));
    return r;
}

__device__ inline void gload_lds16(const void* g, void* s) {
    __builtin_amdgcn_global_load_lds((const __attribute__((address_space(1))) void*)g,
                                     (__attribute__((address_space(3))) void*)s, 16, 0, 0);
}

__device__ inline void bar() {                 // raw barrier + compiler memory fence
    asm volatile("" ::: "memory");
    __builtin_amdgcn_s_barrier();
    asm volatile("" ::: "memory");
}

// st_16x32 swizzle (involution): byte ^= ((byte>>9)&1)<<5 within a 16KB [128][64]bf16 unit
__device__ inline int swz(int b) { return b ^ (((b >> 9) & 1) << 5); }

// ===================== fused weight casts: Wq|Wk|Wv -> wqkv, Wo -> wo =====================
__global__ __launch_bounds__(256) void cast_weights_kernel(
    const float* __restrict__ Wq, const float* __restrict__ Wk,
    const float* __restrict__ Wv, const float* __restrict__ Wo,
    u16* __restrict__ wqkv, u16* __restrict__ wo)
{
    int i = blockIdx.x * 256 + threadIdx.x;    // 786432 float4 chunks total
    const float* src; u16* dst; int j;
    if (i < 262144)      { src = Wq; dst = wqkv;           j = i; }
    else if (i < 393216) { src = Wk; dst = wqkv + 1048576; j = i - 262144; }
    else if (i < 524288) { src = Wv; dst = wqkv + 1572864; j = i - 393216; }
    else                 { src = Wo; dst = wo;             j = i - 524288; }
    float4 v = ((const float4*)src)[j];
    u16x4 o = { f2bf(v.x), f2bf(v.y), f2bf(v.z), f2bf(v.w) };
    ((u16x4*)dst)[j] = o;
}

// ===================== bf16 NT-GEMM: 256x128 tile, counted-vmcnt pipeline (R16-proven) ==
// Out = A(MxK) * W(NxK)^T. BK=64, 512 threads = 8 waves (2M x 4N), wave tile 128x32.
// A triple-buffered (stage kt+2), B double-buffered (stage kt+1). vmcnt(4) at K-tile
// entry; vmcnt(0) only at the last K-tile. st_16x32 swizzle as involution on source
// chunk + read byte. K order identical to R2 kernel -> bit-identical outputs.
// MODE 0: plain f32 Out. MODE 1: fused QKV epilogue (q f32 / k f32 / v bf16+gate*ve).
template<int MODE>
__global__ __launch_bounds__(512) void gemm_bf16_256(
    const u16* __restrict__ A, const u16* __restrict__ W,
    float* __restrict__ Out, int M, int N, int K,
    float* __restrict__ q_out, float* __restrict__ k_out, u16* __restrict__ v_out,
    const float* __restrict__ gate, const float* __restrict__ ve)
{
    __shared__ __align__(16) u16 AL[3][2][128 * 64];   // 96 KB
    __shared__ __align__(16) u16 BL[2][128 * 64];      // 32 KB
    const int tid = threadIdx.x;
    const int lane = tid & 63;
    const int w = tid >> 6;
    const int bm = blockIdx.y * 256;
    const int bn = blockIdx.x * 128;
    const int wm = (w >> 2) * 128;     // A half = w>>2
    const int wn = (w & 3) * 32;
    const int ah = w >> 2;
    const int lr = lane & 15, lg = lane >> 4;
    const int NKT = K >> 6;            // 16

    f32x4 acc[8][2];
    #pragma unroll
    for (int mi = 0; mi < 8; ++mi)
        #pragma unroll
        for (int ni = 0; ni < 2; ++ni) acc[mi][ni] = f32x4{0.f, 0.f, 0.f, 0.f};

    auto stageA = [&](int kt) {        // both halves, 4 loads FIFO
        const int db = kt % 3;
        #pragma unroll
        for (int hf = 0; hf < 2; ++hf)
            #pragma unroll
            for (int ci = 0; ci < 2; ++ci) {
                int c = tid + ci * 512;
                int l = c ^ (((c >> 5) & 1) << 1);
                gload_lds16(A + (size_t)(bm + hf * 128 + (l >> 3)) * K + kt * 64 + (l & 7) * 8,
                            (char*)&AL[db][hf][0] + c * 16);
            }
    };
    auto stageB = [&](int kt) {        // 2 loads
        const int db = kt & 1;
        #pragma unroll
        for (int ci = 0; ci < 2; ++ci) {
            int c = tid + ci * 512;
            int l = c ^ (((c >> 5) & 1) << 1);
            gload_lds16(W + (size_t)(bn + (l >> 3)) * K + kt * 64 + (l & 7) * 8,
                        (char*)&BL[db][0] + c * 16);
        }
    };

    stageA(0);
    stageB(0);
    stageA(1);                          // FIFO: [A0(4), B0(2), A1(4)]

    for (int kt = 0; kt < NKT; ++kt) {
        const int ab = kt % 3, bb = kt & 1;
        if (kt == NKT - 1) asm volatile("s_waitcnt vmcnt(0)" ::: "memory");
        else               asm volatile("s_waitcnt vmcnt(4)" ::: "memory");
        bar();                          // all waves' loads for K-tile kt landed
        #pragma unroll
        for (int ph = 0; ph < 2; ++ph) {
            bf16x8 af[4][2], bfm[2][2];
            #pragma unroll
            for (int mi2 = 0; mi2 < 4; ++mi2) {
                const int row = (ph * 4 + mi2) * 16 + lr;
                #pragma unroll
                for (int kk = 0; kk < 2; ++kk)
                    af[mi2][kk] = *(const bf16x8*)((const char*)&AL[ab][ah][0] +
                                                   swz(row * 128 + kk * 64 + lg * 16));
            }
            #pragma unroll
            for (int ni = 0; ni < 2; ++ni) {
                const int row = wn + ni * 16 + lr;
                #pragma unroll
                for (int kk = 0; kk < 2; ++kk)
                    bfm[ni][kk] = *(const bf16x8*)((const char*)&BL[bb][0] +
                                                   swz(row * 128 + kk * 64 + lg * 16));
            }
            if (ph == 0) { if (kt + 1 < NKT) stageB(kt + 1); }
            else         { if (kt + 2 < NKT) stageA(kt + 2); }
            bar();
            __builtin_amdgcn_s_setprio(1);
            #pragma unroll
            for (int mi2 = 0; mi2 < 4; ++mi2)
                #pragma unroll
                for (int ni = 0; ni < 2; ++ni)
                    #pragma unroll
                    for (int kk = 0; kk < 2; ++kk)
                        acc[ph * 4 + mi2][ni] = __builtin_amdgcn_mfma_f32_16x16x32_bf16(
                            af[mi2][kk], bfm[ni][kk], acc[ph * 4 + mi2][ni], 0, 0, 0);
            __builtin_amdgcn_s_setprio(0);
            bar();
        }
    }

    #pragma unroll
    for (int mi = 0; mi < 8; ++mi)
        #pragma unroll
        for (int ni = 0; ni < 2; ++ni)
            #pragma unroll
            for (int r = 0; r < 4; ++r) {
                const int row = bm + wm + mi * 16 + lg * 4 + r;
                const int col = bn + wn + ni * 16 + lr;
                const float val = acc[mi][ni][r];
                if (MODE == 0) {
                    Out[(size_t)row * N + col] = val;
                } else {
                    if (col < 1024) {
                        q_out[(size_t)row * 1024 + col] = val;
                    } else if (col < 1536) {
                        k_out[(size_t)row * 512 + (col - 1024)] = val;
                    } else {
                        const int cc = col - 1536;
                        v_out[(size_t)row * 512 + cc] =
                            f2bf(val + gate[row * NKV_ + (cc >> 6)] * ve[(size_t)row * 512 + cc]);
                    }
                }
            }
}

// ===================== Router + top-8 mask + gate + fused x->bf16 cast (R12-proven) ====
__global__ __launch_bounds__(64) void logits_mask_gate_kernel(
    const float* __restrict__ x, const float* __restrict__ Wr,
    const float* __restrict__ Wg, float* __restrict__ hm, float* __restrict__ gate,
    u16* __restrict__ xb)
{
    const int token = blockIdx.x;
    const int lane = threadIdx.x;
    const float* xr = x + (size_t)token * C_;
    __shared__ float lg[NH_];
    __shared__ float thr_s;
    float part[NH_];
    #pragma unroll
    for (int h = 0; h < NH_; ++h) part[h] = 0.f;
    for (int c = lane; c < C_; c += 64) {
        float xv = xr[c];
        xb[(size_t)token * C_ + c] = f2bf(xv);   // fused cast
        #pragma unroll
        for (int h = 0; h < NH_; ++h) part[h] = fmaf(xv, Wr[h * C_ + c], part[h]);
    }
    #pragma unroll
    for (int h = 0; h < NH_; ++h) {
        float s = part[h];
        #pragma unroll
        for (int off = 32; off; off >>= 1) s += __shfl_xor(s, off);
        if (lane == 0) lg[h] = s;
    }
    __syncthreads();
    if (lane == 0) {
        unsigned used = 0;
        float last = 0.f;
        for (int p = 0; p < KACT_; ++p) {
            float bv = -3.4e38f; int bi = 0;
            for (int i = 0; i < NH_; ++i)
                if (!(used & (1u << i)) && lg[i] > bv) { bv = lg[i]; bi = i; }
            used |= 1u << bi;
            last = bv;
        }
        thr_s = last;
    }
    __syncthreads();
    if (lane < NH_) hm[(size_t)token * NH_ + lane] = (lg[lane] >= thr_s) ? 1.f : 0.f;
    if (lane < NKV_) {
        float s = 0.f;
        #pragma unroll
        for (int g = 0; g < VG_; ++g) s = fmaf(xr[g], Wg[lane * VG_ + g], s);
        gate[(size_t)token * NKV_ + lane] = 2.f / (1.f + __expf(-s));
    }
}

// ===================== rotary + rms-norm, 16-vec/block, HEAD-major out (R7-proven) ====
__global__ __launch_bounds__(256) void rope_rms_kernel(
    const float* __restrict__ src, int src_stride, u16* __restrict__ dst,
    const float* __restrict__ cosT, const float* __restrict__ sinT,
    int hshift, float scale)
{
    const int tid = threadIdx.x;
    const int vec = blockIdx.x * 16 + (tid >> 4);   // = m*heads + h
    const int idx = tid & 15;
    const int heads = 1 << hshift;
    const int m = vec >> hshift;
    const int hh = vec & (heads - 1);
    const int t = m & (T_ - 1);
    const int bb = m >> 11;
    const float4 v4 = *(const float4*)(src + (size_t)m * src_stride + hh * 64 + idx * 4);
    const float4 c4 = *(const float4*)(cosT + t * 32 + (idx & 7) * 4);
    const float4 s4 = *(const float4*)(sinT + t * 32 + (idx & 7) * 4);
    const float p0 = __shfl_xor(v4.x, 8);
    const float p1 = __shfl_xor(v4.y, 8);
    const float p2 = __shfl_xor(v4.z, 8);
    const float p3 = __shfl_xor(v4.w, 8);
    float r0, r1, r2, r3;
    if (idx < 8) {
        r0 = fmaf(v4.x, c4.x, p0 * s4.x); r1 = fmaf(v4.y, c4.y, p1 * s4.y);
        r2 = fmaf(v4.z, c4.z, p2 * s4.z); r3 = fmaf(v4.w, c4.w, p3 * s4.w);
    } else {
        r0 = fmaf(v4.x, c4.x, -p0 * s4.x); r1 = fmaf(v4.y, c4.y, -p1 * s4.y);
        r2 = fmaf(v4.z, c4.z, -p2 * s4.z); r3 = fmaf(v4.w, c4.w, -p3 * s4.w);
    }
    float ss = fmaf(r0, r0, fmaf(r1, r1, fmaf(r2, r2, r3 * r3)));
    ss += __shfl_xor(ss, 1);
    ss += __shfl_xor(ss, 2);
    ss += __shfl_xor(ss, 4);
    ss += __shfl_xor(ss, 8);
    const float sc = rsqrtf(ss * (1.0f / HD_) + EPS_) * scale;
    u16x4 o = { f2bf(r0 * sc), f2bf(r1 * sc), f2bf(r2 * sc), f2bf(r3 * sc) };
    *(u16x4*)(dst + ((size_t)(bb * heads + hh) * T_ + t) * HD_ + idx * 4) = o;
}

// ===================== vb [m][kv][d] -> vbT [b][kv][d][t] (R2 verbatim) =====================
__global__ __launch_bounds__(256) void transpose_v_kernel(
    const u16* __restrict__ vb, u16* __restrict__ vt)
{
    __shared__ __align__(16) u16 Ls[64 * 64];
    const int bid = blockIdx.x;
    const int tt = bid & 31;
    const int kv = (bid >> 5) & 7;
    const int b = bid >> 8;
    const int tid = threadIdx.x;
    const int t0 = tt * 64;
    #pragma unroll
    for (int it = 0; it < 2; ++it) {
        int c = tid + it * 256;
        int tl = c >> 3, dg = c & 7;
        bf16x8 u = *(const bf16x8*)(vb + (((size_t)(b * T_) + t0 + tl) * NKV_ + kv) * HD_ + dg * 8);
        *(bf16x8*)((char*)Ls + ((tl * 128 + dg * 16) ^ ((tl & 7) << 4))) = u;
    }
    __syncthreads();
    #pragma unroll
    for (int it = 0; it < 2; ++it) {
        int c = tid + it * 256;
        int d = c >> 3, tg = c & 7;
        u16 vals[8];
        #pragma unroll
        for (int j = 0; j < 8; ++j) {
            int tl = tg * 8 + j;
            vals[j] = *(const u16*)((char*)Ls + ((tl * 128 + d * 2) ^ ((tl & 7) << 4)));
        }
        *(bf16x8*)(vt + (((size_t)(b * NKV_) + kv) * HD_ + d) * (size_t)T_ + t0 + tg * 8) = *(bf16x8*)vals;
    }
}

// ===================== MFMA flash attention v6: QBLK=128, 8 waves =====================
// Per-tile math is R12 VERBATIM; generalization is wave-uniform only:
//   rel = q0 + w*16 + 15 - kt*64;  mtmax = min(3, rel>>4);  kimax = min(1, rel>>5)
// (equal to the old diag?w:3 / diag?(w>>1):1 at QBLK=64). Waves with rel<0 skip compute
// (fully-masked tile) but still hit both barriers. Each K/V tile staged ONCE per 128
// q-rows: staging traffic + barriers per unit work halved; LDS 36.9KB -> 4 blk x 8 waves
// = 32 waves/CU cap (was 20). Elementwise causal mask (branchy form BANNED: R9/R10).
// LDS staging REQUIRED (R13). Per-q-row tile sequence unchanged -> bit-identical output.
__global__ __launch_bounds__(512) void attn_mfma_kernel(
    const u16* __restrict__ qb, const u16* __restrict__ kb,
    const u16* __restrict__ vbT, const float* __restrict__ hm,
    u16* __restrict__ yb)
{
    __shared__ __align__(16) u16 Ks[64 * 72];
    __shared__ __align__(16) u16 Vt[64 * 72];
    __shared__ __align__(16) u16 Ps[8 * 16 * 72];
    const int bid = blockIdx.x;
    const int qblk = 15 - (bid & 15);          // reversed: longest blocks first
    const int h = (bid >> 4) & 15;
    const int b = bid >> 8;
    const int kv = h >> 1;
    const int tid = threadIdx.x;
    const int lane = tid & 63;
    const int w = tid >> 6;                    // 0..7
    const int lr = lane & 15;
    const int lg = lane >> 4;
    const int q0 = qblk * 128;
    const int qt_max = 2 * qblk + 1;

    bf16x8 qf[2];
    {
        const u16* src = qb + ((size_t)(b * NH_ + h) * T_ + q0 + w * 16 + lr) * HD_ + lg * 8;
        qf[0] = *(const bf16x8*)(src);
        qf[1] = *(const bf16x8*)(src + 32);
    }
    f32x4 yacc[4];
    #pragma unroll
    for (int dt = 0; dt < 4; ++dt) yacc[dt] = f32x4{0.f, 0.f, 0.f, 0.f};
    float m = -1e30f, l = 0.f;

    const u16* kbase = kb + (size_t)(b * NKV_ + kv) * T_ * HD_;            // head-major [t][64]
    const u16* vbase = vbT + ((size_t)(b * NKV_) + kv) * (size_t)HD_ * T_; // [d][t]
    u16* Pw = Ps + w * 16 * 72;
    const int qrow_g = q0 + w * 16 + lr;

    // staging: 512 threads cover all 512 16B chunks of K and V each
    const int a0 = tid >> 3, g0 = tid & 7;
    bf16x8 kreg, vreg;
    auto LOADT = [&](int kt) {
        kreg = *(const bf16x8*)(kbase + (size_t)(kt * 64 + a0) * HD_ + g0 * 8);
        vreg = *(const bf16x8*)(vbase + (size_t)a0 * T_ + kt * 64 + g0 * 8);
    };
    auto WRITET = [&]() {
        *(bf16x8*)&Ks[a0 * 72 + g0 * 8] = kreg;
        *(bf16x8*)&Vt[a0 * 72 + g0 * 8] = vreg;
    };

    LOADT(0);
    WRITET();
    for (int kt = 0; kt <= qt_max; ++kt) {
        __syncthreads();                       // tile kt visible in LDS
        if (kt < qt_max) LOADT(kt + 1);        // prefetch next tile into regs
        const int rel = q0 + w * 16 + 15 - kt * 64;
        if (rel >= 0) {                        // wave-uniform skip of fully-masked tiles
            const int mtmax = min(3, rel >> 4);
            f32x4 st[4];
            #pragma unroll
            for (int mt = 0; mt < 4; ++mt) st[mt] = f32x4{0.f, 0.f, 0.f, 0.f};
            __builtin_amdgcn_s_setprio(1);
            #pragma unroll
            for (int mt = 0; mt < 4; ++mt) {
                if (mt <= mtmax) {
                    bf16x8 kf0 = *(const bf16x8*)&Ks[(mt * 16 + lr) * 72 + lg * 8];
                    bf16x8 kf1 = *(const bf16x8*)&Ks[(mt * 16 + lr) * 72 + lg * 8 + 32];
                    st[mt] = __builtin_amdgcn_mfma_f32_16x16x32_bf16(kf0, qf[0], st[mt], 0, 0, 0);
                    st[mt] = __builtin_amdgcn_mfma_f32_16x16x32_bf16(kf1, qf[1], st[mt], 0, 0, 0);
                }
            }
            __builtin_amdgcn_s_setprio(0);
            // mask + per-q max (elementwise PROVEN form)
            float smax = -1e30f;
            #pragma unroll
            for (int mt = 0; mt < 4; ++mt) {
                #pragma unroll
                for (int r = 0; r < 4; ++r) {
                    int keyg = kt * 64 + mt * 16 + lg * 4 + r;
                    float s = (mt <= mtmax && keyg <= qrow_g) ? st[mt][r] : -1e30f;
                    st[mt][r] = s;
                    smax = fmaxf(smax, s);
                }
            }
            smax = fmaxf(smax, __shfl_xor(smax, 16));
            smax = fmaxf(smax, __shfl_xor(smax, 32));
            if (!__all(smax <= m + 8.f)) {     // defer-max: P bounded by 2^8, bf16-safe
                const float mnew = fmaxf(m, smax);
                const float corr = fast_exp2(m - mnew);
                l *= corr;
                float cr[4];
                #pragma unroll
                for (int r = 0; r < 4; ++r) cr[r] = __shfl(corr, lg * 4 + r);
                #pragma unroll
                for (int dt = 0; dt < 4; ++dt)
                    #pragma unroll
                    for (int r = 0; r < 4; ++r) yacc[dt][r] *= cr[r];
                m = mnew;
            }
            float psum = 0.f;
            #pragma unroll
            for (int mt = 0; mt < 4; ++mt) {
                float p0 = fast_exp2(st[mt][0] - m);
                float p1 = fast_exp2(st[mt][1] - m);
                float p2 = fast_exp2(st[mt][2] - m);
                float p3 = fast_exp2(st[mt][3] - m);
                psum += (p0 + p1) + (p2 + p3);
                u16x4 pk = { f2bf(p0), f2bf(p1), f2bf(p2), f2bf(p3) };
                *(u16x4*)&Pw[lr * 72 + mt * 16 + lg * 4] = pk;
            }
            psum += __shfl_xor(psum, 16);
            psum += __shfl_xor(psum, 32);
            l += psum;
            // PV: Y[q][d] += P[q][s] * V[s][d]
            const int kimax = min(1, rel >> 5);
            __builtin_amdgcn_s_setprio(1);
            #pragma unroll
            for (int ki = 0; ki < 2; ++ki) {
                if (ki <= kimax) {
                    bf16x8 pf = *(const bf16x8*)&Pw[lr * 72 + ki * 32 + lg * 8];
                    #pragma unroll
                    for (int dt = 0; dt < 4; ++dt) {
                        bf16x8 vf = *(const bf16x8*)&Vt[(dt * 16 + lr) * 72 + ki * 32 + lg * 8];
                        yacc[dt] = __builtin_amdgcn_mfma_f32_16x16x32_bf16(pf, vf, yacc[dt], 0, 0, 0);
                    }
                }
            }
            __builtin_amdgcn_s_setprio(0);
        }
        __syncthreads();                       // all waves done reading tile kt
        if (kt < qt_max) WRITET();             // overwrite LDS with tile kt+1
    }
    const float linv = 1.f / l;
    #pragma unroll
    for (int r = 0; r < 4; ++r) {
        const float lrv = __shfl(linv, lg * 4 + r);
        const int t = q0 + w * 16 + lg * 4 + r;
        const float hmv = hm[((size_t)(b * T_) + t) * NH_ + h];
        const float sc = lrv * hmv;
        #pragma unroll
        for (int dt = 0; dt < 4; ++dt)
            yb[(((size_t)(b * T_) + t) * NH_ + h) * HD_ + dt * 16 + lr] = f2bf(yacc[dt][r] * sc);
    }
}

extern "C" void kernel_launch(void* const* d_in, const int* in_sizes, int n_in,
                              void* d_out, int out_size, void* d_ws, size_t ws_size,
                              hipStream_t stream) {
    const float* x    = (const float*)d_in[0];
    const float* ve   = (const float*)d_in[1];
    const float* cosT = (const float*)d_in[2];
    const float* sinT = (const float*)d_in[3];
    const float* Wq   = (const float*)d_in[4];
    const float* Wk   = (const float*)d_in[5];
    const float* Wv   = (const float*)d_in[6];
    const float* Wo   = (const float*)d_in[7];
    const float* Wr   = (const float*)d_in[8];
    const float* Wg   = (const float*)d_in[9];
    float* out = (float*)d_out;
    float* hm  = out + (size_t)B_ * T_ * C_;

    const int M = B_ * T_;  // 8192
    float* ws = (float*)d_ws;
    float* qf32  = ws;                  // 8388608 f   [after rope_q: yb bf16]
    float* kf32  = qf32 + 8388608;      // 4194304 f   [after rope_k: vbT bf16]
    float* xbr   = kf32 + 4194304;      // 4194304 f (bf16 x) [after QKV gemm: qb bf16]
    float* wqkvr = xbr + 4194304;       // 1048576 f (bf16 Wqkv)
    float* wor   = wqkvr + 1048576;     // 524288 f  (bf16 Wo)
    float* gate  = wor + 524288;        // 65536 f
    float* vbr   = gate + 65536;        // 2097152 f (bf16 v, token-major)
    float* kbr   = vbr + 2097152;       // 2097152 f (bf16 k roped, head-major)

    u16* xb    = (u16*)xbr;
    u16* Wqkvb = (u16*)wqkvr;
    u16* Wob   = (u16*)wor;
    u16* vb    = (u16*)vbr;
    u16* qb    = (u16*)xbr;    // overlays xb (dead after QKV GEMM), head-major
    u16* kb    = (u16*)kbr;    // head-major
    u16* vbT   = (u16*)kf32;   // overlays kf32 (dead after rope_k)
    u16* yb    = (u16*)qf32;   // overlays qf32 (dead after rope_q)

    // ---- weight casts ----
    cast_weights_kernel<<<3072, 256, 0, stream>>>(Wq, Wk, Wv, Wo, Wqkvb, Wob);
    // ---- router (gate feeds the fused V epilogue; also emits xb) ----
    logits_mask_gate_kernel<<<M, 64, 0, stream>>>(x, Wr, Wg, hm, gate, xb);
    // ---- fused QKV projection (256x128 counted-vmcnt pipeline) ----
    gemm_bf16_256<1><<<dim3(2048 / 128, M / 256), 512, 0, stream>>>(
        xb, Wqkvb, nullptr, M, 2048, C_, qf32, kf32, vb, gate, ve);
    // ---- rope+rms -> bf16 head-major (q folded with 1/sqrt(HD)*log2e for exp2 softmax) ----
    rope_rms_kernel<<<(M * NH_) / 16, 256, 0, stream>>>(qf32, 1024, qb, cosT, sinT, 4, 0.125f * LOG2E_);
    rope_rms_kernel<<<(M * NKV_) / 16, 256, 0, stream>>>(kf32, 512, kb, cosT, sinT, 3, 1.0f);
    // ---- V transpose ----
    transpose_v_kernel<<<B_ * NKV_ * (T_ / 64), 256, 0, stream>>>(vb, vbT);
    // ---- flash attention (QBLK=128, 8 waves) ----
    attn_mfma_kernel<<<B_ * NH_ * (T_ / 128), 512, 0, stream>>>(qb, kb, vbT, hm, yb);
    // ---- output projection (256x128 pipeline) ----
    gemm_bf16_256<0><<<dim3(C_ / 128, M / 256), 512, 0, stream>>>(
        yb, Wob, out, M, C_, C_, nullptr, nullptr, nullptr, nullptr, nullptr);
}

// Round 18
// 271.563 us; speedup vs baseline: 1.3129x; 1.1371x over previous
//
#include <hip/hip_runtime.h>
#include <math.h>

#define B_ 4
#define T_ 2048
#define C_ 1024
#define NH_ 16
#define NKV_ 8
#define HD_ 64
#define KACT_ 8
#define VG_ 32
#define EPS_ 1e-6f
#define LOG2E_ 1.44269504088896340736f

typedef __attribute__((ext_vector_type(8))) short bf16x8;
typedef __attribute__((ext_vector_type(4))) float f32x4;
typedef __attribute__((ext_vector_type(4))) unsigned short u16x4;
typedef unsigned short u16;
typedef unsigned int u32;

__device__ inline u16 f2bf(float f) {
    u32 u = __float_as_uint(f);
    u += 0x7fffu + ((u >> 16) & 1u);   // RNE (finite data)
    return (u16)(u >> 16);
}

__device__ inline u16 f2bf_t(float f) {        // truncating (P>=0 softmax weights only)
    return (u16)(__float_as_uint(f) >> 16);
}

__device__ inline float fast_exp2(float x) {   // bare v_exp_f32 (D = 2^S0), no libm guards
    float r;
    asm("v_exp_f32 %0, %1" : "=v"(r) : "v"(x));
    return r;
}

__device__ inline void gload_lds16(const void* g, void* s) {
    __builtin_amdgcn_global_load_lds((const __attribute__((address_space(1))) void*)g,
                                     (__attribute__((address_space(3))) void*)s, 16, 0, 0);
}

__device__ inline void bar() {                 // raw barrier + compiler memory fence
    asm volatile("" ::: "memory");
    __builtin_amdgcn_s_barrier();
    asm volatile("" ::: "memory");
}

// st_16x32 swizzle (involution): byte ^= ((byte>>9)&1)<<5 within a 16KB [128][64]bf16 unit
__device__ inline int swz(int b) { return b ^ (((b >> 9) & 1) << 5); }

// ===================== fused weight casts: Wq|Wk|Wv -> wqkv, Wo -> wo =====================
__global__ __launch_bounds__(256) void cast_weights_kernel(
    const float* __restrict__ Wq, const float* __restrict__ Wk,
    const float* __restrict__ Wv, const float* __restrict__ Wo,
    u16* __restrict__ wqkv, u16* __restrict__ wo)
{
    int i = blockIdx.x * 256 + threadIdx.x;    // 786432 float4 chunks total
    const float* src; u16* dst; int j;
    if (i < 262144)      { src = Wq; dst = wqkv;           j = i; }
    else if (i < 393216) { src = Wk; dst = wqkv + 1048576; j = i - 262144; }
    else if (i < 524288) { src = Wv; dst = wqkv + 1572864; j = i - 393216; }
    else                 { src = Wo; dst = wo;             j = i - 524288; }
    float4 v = ((const float4*)src)[j];
    u16x4 o = { f2bf(v.x), f2bf(v.y), f2bf(v.z), f2bf(v.w) };
    ((u16x4*)dst)[j] = o;
}

// ===================== bf16 NT-GEMM: 256x128 tile, counted-vmcnt pipeline (R16-proven) ==
// Out = A(MxK) * W(NxK)^T. BK=64, 512 threads = 8 waves (2M x 4N), wave tile 128x32.
// A triple-buffered (stage kt+2), B double-buffered (stage kt+1). vmcnt(4) at K-tile
// entry; vmcnt(0) only at the last K-tile. st_16x32 swizzle as involution on source
// chunk + read byte. K order identical to R2 kernel -> bit-identical accumulators.
// MODE 0: plain f32 Out. MODE 1: fused QKV epilogue:
//   q f32 token-major; k f32 token-major; v -> gate*ve add, bf16, written DIRECTLY
//   transposed as vbT[b][kv][d][t] (4 consecutive tokens per thread = packed 8B store)
//   -> transpose_v kernel deleted.
template<int MODE>
__global__ __launch_bounds__(512) void gemm_bf16_256(
    const u16* __restrict__ A, const u16* __restrict__ W,
    float* __restrict__ Out, int M, int N, int K,
    float* __restrict__ q_out, float* __restrict__ k_out, u16* __restrict__ vT_out,
    const float* __restrict__ gate, const float* __restrict__ ve)
{
    __shared__ __align__(16) u16 AL[3][2][128 * 64];   // 96 KB
    __shared__ __align__(16) u16 BL[2][128 * 64];      // 32 KB
    const int tid = threadIdx.x;
    const int lane = tid & 63;
    const int w = tid >> 6;
    const int bm = blockIdx.y * 256;
    const int bn = blockIdx.x * 128;
    const int wm = (w >> 2) * 128;     // A half = w>>2
    const int wn = (w & 3) * 32;
    const int ah = w >> 2;
    const int lr = lane & 15, lg = lane >> 4;
    const int NKT = K >> 6;            // 16

    f32x4 acc[8][2];
    #pragma unroll
    for (int mi = 0; mi < 8; ++mi)
        #pragma unroll
        for (int ni = 0; ni < 2; ++ni) acc[mi][ni] = f32x4{0.f, 0.f, 0.f, 0.f};

    auto stageA = [&](int kt) {        // both halves, 4 loads FIFO
        const int db = kt % 3;
        #pragma unroll
        for (int hf = 0; hf < 2; ++hf)
            #pragma unroll
            for (int ci = 0; ci < 2; ++ci) {
                int c = tid + ci * 512;
                int l = c ^ (((c >> 5) & 1) << 1);
                gload_lds16(A + (size_t)(bm + hf * 128 + (l >> 3)) * K + kt * 64 + (l & 7) * 8,
                            (char*)&AL[db][hf][0] + c * 16);
            }
    };
    auto stageB = [&](int kt) {        // 2 loads
        const int db = kt & 1;
        #pragma unroll
        for (int ci = 0; ci < 2; ++ci) {
            int c = tid + ci * 512;
            int l = c ^ (((c >> 5) & 1) << 1);
            gload_lds16(W + (size_t)(bn + (l >> 3)) * K + kt * 64 + (l & 7) * 8,
                        (char*)&BL[db][0] + c * 16);
        }
    };

    stageA(0);
    stageB(0);
    stageA(1);                          // FIFO: [A0(4), B0(2), A1(4)]

    for (int kt = 0; kt < NKT; ++kt) {
        const int ab = kt % 3, bb = kt & 1;
        if (kt == NKT - 1) asm volatile("s_waitcnt vmcnt(0)" ::: "memory");
        else               asm volatile("s_waitcnt vmcnt(4)" ::: "memory");
        bar();                          // all waves' loads for K-tile kt landed
        #pragma unroll
        for (int ph = 0; ph < 2; ++ph) {
            bf16x8 af[4][2], bfm[2][2];
            #pragma unroll
            for (int mi2 = 0; mi2 < 4; ++mi2) {
                const int row = (ph * 4 + mi2) * 16 + lr;
                #pragma unroll
                for (int kk = 0; kk < 2; ++kk)
                    af[mi2][kk] = *(const bf16x8*)((const char*)&AL[ab][ah][0] +
                                                   swz(row * 128 + kk * 64 + lg * 16));
            }
            #pragma unroll
            for (int ni = 0; ni < 2; ++ni) {
                const int row = wn + ni * 16 + lr;
                #pragma unroll
                for (int kk = 0; kk < 2; ++kk)
                    bfm[ni][kk] = *(const bf16x8*)((const char*)&BL[bb][0] +
                                                   swz(row * 128 + kk * 64 + lg * 16));
            }
            if (ph == 0) { if (kt + 1 < NKT) stageB(kt + 1); }
            else         { if (kt + 2 < NKT) stageA(kt + 2); }
            bar();
            __builtin_amdgcn_s_setprio(1);
            #pragma unroll
            for (int mi2 = 0; mi2 < 4; ++mi2)
                #pragma unroll
                for (int ni = 0; ni < 2; ++ni)
                    #pragma unroll
                    for (int kk = 0; kk < 2; ++kk)
                        acc[ph * 4 + mi2][ni] = __builtin_amdgcn_mfma_f32_16x16x32_bf16(
                            af[mi2][kk], bfm[ni][kk], acc[ph * 4 + mi2][ni], 0, 0, 0);
            __builtin_amdgcn_s_setprio(0);
            bar();
        }
    }

    #pragma unroll
    for (int mi = 0; mi < 8; ++mi)
        #pragma unroll
        for (int ni = 0; ni < 2; ++ni) {
            const int row0 = bm + wm + mi * 16 + lg * 4;   // 4 consecutive tokens, same b
            const int col = bn + wn + ni * 16 + lr;
            if (MODE == 0) {
                #pragma unroll
                for (int r = 0; r < 4; ++r)
                    Out[(size_t)(row0 + r) * N + col] = acc[mi][ni][r];
            } else {
                if (col < 1024) {
                    #pragma unroll
                    for (int r = 0; r < 4; ++r)
                        q_out[(size_t)(row0 + r) * 1024 + col] = acc[mi][ni][r];
                } else if (col < 1536) {
                    #pragma unroll
                    for (int r = 0; r < 4; ++r)
                        k_out[(size_t)(row0 + r) * 512 + (col - 1024)] = acc[mi][ni][r];
                } else {
                    const int cc = col - 1536;
                    const int kv = cc >> 6, d = cc & 63;
                    u16x4 pk;
                    #pragma unroll
                    for (int r = 0; r < 4; ++r) {
                        const int row = row0 + r;
                        pk[r] = f2bf(acc[mi][ni][r] +
                                     gate[row * NKV_ + kv] * ve[(size_t)row * 512 + cc]);
                    }
                    *(u16x4*)(vT_out + ((size_t)((row0 >> 11) * NKV_ + kv) * HD_ + d) * T_ +
                              (row0 & (T_ - 1))) = pk;
                }
            }
        }
}

// ===================== Router + top-8 mask + gate + fused x->bf16 cast (R12-proven) ====
__global__ __launch_bounds__(64) void logits_mask_gate_kernel(
    const float* __restrict__ x, const float* __restrict__ Wr,
    const float* __restrict__ Wg, float* __restrict__ hm, float* __restrict__ gate,
    u16* __restrict__ xb)
{
    const int token = blockIdx.x;
    const int lane = threadIdx.x;
    const float* xr = x + (size_t)token * C_;
    __shared__ float lg[NH_];
    __shared__ float thr_s;
    float part[NH_];
    #pragma unroll
    for (int h = 0; h < NH_; ++h) part[h] = 0.f;
    for (int c = lane; c < C_; c += 64) {
        float xv = xr[c];
        xb[(size_t)token * C_ + c] = f2bf(xv);   // fused cast
        #pragma unroll
        for (int h = 0; h < NH_; ++h) part[h] = fmaf(xv, Wr[h * C_ + c], part[h]);
    }
    #pragma unroll
    for (int h = 0; h < NH_; ++h) {
        float s = part[h];
        #pragma unroll
        for (int off = 32; off; off >>= 1) s += __shfl_xor(s, off);
        if (lane == 0) lg[h] = s;
    }
    __syncthreads();
    if (lane == 0) {
        unsigned used = 0;
        float last = 0.f;
        for (int p = 0; p < KACT_; ++p) {
            float bv = -3.4e38f; int bi = 0;
            for (int i = 0; i < NH_; ++i)
                if (!(used & (1u << i)) && lg[i] > bv) { bv = lg[i]; bi = i; }
            used |= 1u << bi;
            last = bv;
        }
        thr_s = last;
    }
    __syncthreads();
    if (lane < NH_) hm[(size_t)token * NH_ + lane] = (lg[lane] >= thr_s) ? 1.f : 0.f;
    if (lane < NKV_) {
        float s = 0.f;
        #pragma unroll
        for (int g = 0; g < VG_; ++g) s = fmaf(xr[g], Wg[lane * VG_ + g], s);
        gate[(size_t)token * NKV_ + lane] = 2.f / (1.f + __expf(-s));
    }
}

// ===================== rotary + rms-norm, 16-vec/block, HEAD-major out (R7-proven) ====
__global__ __launch_bounds__(256) void rope_rms_kernel(
    const float* __restrict__ src, int src_stride, u16* __restrict__ dst,
    const float* __restrict__ cosT, const float* __restrict__ sinT,
    int hshift, float scale)
{
    const int tid = threadIdx.x;
    const int vec = blockIdx.x * 16 + (tid >> 4);   // = m*heads + h
    const int idx = tid & 15;
    const int heads = 1 << hshift;
    const int m = vec >> hshift;
    const int hh = vec & (heads - 1);
    const int t = m & (T_ - 1);
    const int bb = m >> 11;
    const float4 v4 = *(const float4*)(src + (size_t)m * src_stride + hh * 64 + idx * 4);
    const float4 c4 = *(const float4*)(cosT + t * 32 + (idx & 7) * 4);
    const float4 s4 = *(const float4*)(sinT + t * 32 + (idx & 7) * 4);
    const float p0 = __shfl_xor(v4.x, 8);
    const float p1 = __shfl_xor(v4.y, 8);
    const float p2 = __shfl_xor(v4.z, 8);
    const float p3 = __shfl_xor(v4.w, 8);
    float r0, r1, r2, r3;
    if (idx < 8) {
        r0 = fmaf(v4.x, c4.x, p0 * s4.x); r1 = fmaf(v4.y, c4.y, p1 * s4.y);
        r2 = fmaf(v4.z, c4.z, p2 * s4.z); r3 = fmaf(v4.w, c4.w, p3 * s4.w);
    } else {
        r0 = fmaf(v4.x, c4.x, -p0 * s4.x); r1 = fmaf(v4.y, c4.y, -p1 * s4.y);
        r2 = fmaf(v4.z, c4.z, -p2 * s4.z); r3 = fmaf(v4.w, c4.w, -p3 * s4.w);
    }
    float ss = fmaf(r0, r0, fmaf(r1, r1, fmaf(r2, r2, r3 * r3)));
    ss += __shfl_xor(ss, 1);
    ss += __shfl_xor(ss, 2);
    ss += __shfl_xor(ss, 4);
    ss += __shfl_xor(ss, 8);
    const float sc = rsqrtf(ss * (1.0f / HD_) + EPS_) * scale;
    u16x4 o = { f2bf(r0 * sc), f2bf(r1 * sc), f2bf(r2 * sc), f2bf(r3 * sc) };
    *(u16x4*)(dst + ((size_t)(bb * heads + hh) * T_ + t) * HD_ + idx * 4) = o;
}

// ===================== MFMA flash attention v6 (R17-proven) + truncating P pack =======
// Per-tile math R12-lineage; wave-uniform rel/mtmax/kimax generalization (R17-proven).
// Elementwise causal mask (branchy form BANNED: R9/R10). LDS staging REQUIRED (R13).
// P pack: truncating f2bf_t (P>=0; bias cancels between numerator and l).
__global__ __launch_bounds__(512) void attn_mfma_kernel(
    const u16* __restrict__ qb, const u16* __restrict__ kb,
    const u16* __restrict__ vbT, const float* __restrict__ hm,
    u16* __restrict__ yb)
{
    __shared__ __align__(16) u16 Ks[64 * 72];
    __shared__ __align__(16) u16 Vt[64 * 72];
    __shared__ __align__(16) u16 Ps[8 * 16 * 72];
    const int bid = blockIdx.x;
    const int qblk = 15 - (bid & 15);          // reversed: longest blocks first
    const int h = (bid >> 4) & 15;
    const int b = bid >> 8;
    const int kv = h >> 1;
    const int tid = threadIdx.x;
    const int lane = tid & 63;
    const int w = tid >> 6;                    // 0..7
    const int lr = lane & 15;
    const int lg = lane >> 4;
    const int q0 = qblk * 128;
    const int qt_max = 2 * qblk + 1;

    bf16x8 qf[2];
    {
        const u16* src = qb + ((size_t)(b * NH_ + h) * T_ + q0 + w * 16 + lr) * HD_ + lg * 8;
        qf[0] = *(const bf16x8*)(src);
        qf[1] = *(const bf16x8*)(src + 32);
    }
    f32x4 yacc[4];
    #pragma unroll
    for (int dt = 0; dt < 4; ++dt) yacc[dt] = f32x4{0.f, 0.f, 0.f, 0.f};
    float m = -1e30f, l = 0.f;

    const u16* kbase = kb + (size_t)(b * NKV_ + kv) * T_ * HD_;            // head-major [t][64]
    const u16* vbase = vbT + ((size_t)(b * NKV_) + kv) * (size_t)HD_ * T_; // [d][t]
    u16* Pw = Ps + w * 16 * 72;
    const int qrow_g = q0 + w * 16 + lr;

    const int a0 = tid >> 3, g0 = tid & 7;
    bf16x8 kreg, vreg;
    auto LOADT = [&](int kt) {
        kreg = *(const bf16x8*)(kbase + (size_t)(kt * 64 + a0) * HD_ + g0 * 8);
        vreg = *(const bf16x8*)(vbase + (size_t)a0 * T_ + kt * 64 + g0 * 8);
    };
    auto WRITET = [&]() {
        *(bf16x8*)&Ks[a0 * 72 + g0 * 8] = kreg;
        *(bf16x8*)&Vt[a0 * 72 + g0 * 8] = vreg;
    };

    LOADT(0);
    WRITET();
    for (int kt = 0; kt <= qt_max; ++kt) {
        __syncthreads();                       // tile kt visible in LDS
        if (kt < qt_max) LOADT(kt + 1);        // prefetch next tile into regs
        const int rel = q0 + w * 16 + 15 - kt * 64;
        if (rel >= 0) {                        // wave-uniform skip of fully-masked tiles
            const int mtmax = min(3, rel >> 4);
            f32x4 st[4];
            #pragma unroll
            for (int mt = 0; mt < 4; ++mt) st[mt] = f32x4{0.f, 0.f, 0.f, 0.f};
            __builtin_amdgcn_s_setprio(1);
            #pragma unroll
            for (int mt = 0; mt < 4; ++mt) {
                if (mt <= mtmax) {
                    bf16x8 kf0 = *(const bf16x8*)&Ks[(mt * 16 + lr) * 72 + lg * 8];
                    bf16x8 kf1 = *(const bf16x8*)&Ks[(mt * 16 + lr) * 72 + lg * 8 + 32];
                    st[mt] = __builtin_amdgcn_mfma_f32_16x16x32_bf16(kf0, qf[0], st[mt], 0, 0, 0);
                    st[mt] = __builtin_amdgcn_mfma_f32_16x16x32_bf16(kf1, qf[1], st[mt], 0, 0, 0);
                }
            }
            __builtin_amdgcn_s_setprio(0);
            // mask + per-q max (elementwise PROVEN form)
            float smax = -1e30f;
            #pragma unroll
            for (int mt = 0; mt < 4; ++mt) {
                #pragma unroll
                for (int r = 0; r < 4; ++r) {
                    int keyg = kt * 64 + mt * 16 + lg * 4 + r;
                    float s = (mt <= mtmax && keyg <= qrow_g) ? st[mt][r] : -1e30f;
                    st[mt][r] = s;
                    smax = fmaxf(smax, s);
                }
            }
            smax = fmaxf(smax, __shfl_xor(smax, 16));
            smax = fmaxf(smax, __shfl_xor(smax, 32));
            if (!__all(smax <= m + 8.f)) {     // defer-max: P bounded by 2^8, bf16-safe
                const float mnew = fmaxf(m, smax);
                const float corr = fast_exp2(m - mnew);
                l *= corr;
                float cr[4];
                #pragma unroll
                for (int r = 0; r < 4; ++r) cr[r] = __shfl(corr, lg * 4 + r);
                #pragma unroll
                for (int dt = 0; dt < 4; ++dt)
                    #pragma unroll
                    for (int r = 0; r < 4; ++r) yacc[dt][r] *= cr[r];
                m = mnew;
            }
            float psum = 0.f;
            #pragma unroll
            for (int mt = 0; mt < 4; ++mt) {
                float p0 = fast_exp2(st[mt][0] - m);
                float p1 = fast_exp2(st[mt][1] - m);
                float p2 = fast_exp2(st[mt][2] - m);
                float p3 = fast_exp2(st[mt][3] - m);
                psum += (p0 + p1) + (p2 + p3);
                u16x4 pk = { f2bf_t(p0), f2bf_t(p1), f2bf_t(p2), f2bf_t(p3) };
                *(u16x4*)&Pw[lr * 72 + mt * 16 + lg * 4] = pk;
            }
            psum += __shfl_xor(psum, 16);
            psum += __shfl_xor(psum, 32);
            l += psum;
            // PV: Y[q][d] += P[q][s] * V[s][d]
            const int kimax = min(1, rel >> 5);
            __builtin_amdgcn_s_setprio(1);
            #pragma unroll
            for (int ki = 0; ki < 2; ++ki) {
                if (ki <= kimax) {
                    bf16x8 pf = *(const bf16x8*)&Pw[lr * 72 + ki * 32 + lg * 8];
                    #pragma unroll
                    for (int dt = 0; dt < 4; ++dt) {
                        bf16x8 vf = *(const bf16x8*)&Vt[(dt * 16 + lr) * 72 + ki * 32 + lg * 8];
                        yacc[dt] = __builtin_amdgcn_mfma_f32_16x16x32_bf16(pf, vf, yacc[dt], 0, 0, 0);
                    }
                }
            }
            __builtin_amdgcn_s_setprio(0);
        }
        __syncthreads();                       // all waves done reading tile kt
        if (kt < qt_max) WRITET();             // overwrite LDS with tile kt+1
    }
    const float linv = 1.f / l;
    #pragma unroll
    for (int r = 0; r < 4; ++r) {
        const float lrv = __shfl(linv, lg * 4 + r);
        const int t = q0 + w * 16 + lg * 4 + r;
        const float hmv = hm[((size_t)(b * T_) + t) * NH_ + h];
        const float sc = lrv * hmv;
        #pragma unroll
        for (int dt = 0; dt < 4; ++dt)
            yb[(((size_t)(b * T_) + t) * NH_ + h) * HD_ + dt * 16 + lr] = f2bf(yacc[dt][r] * sc);
    }
}

extern "C" void kernel_launch(void* const* d_in, const int* in_sizes, int n_in,
                              void* d_out, int out_size, void* d_ws, size_t ws_size,
                              hipStream_t stream) {
    const float* x    = (const float*)d_in[0];
    const float* ve   = (const float*)d_in[1];
    const float* cosT = (const float*)d_in[2];
    const float* sinT = (const float*)d_in[3];
    const float* Wq   = (const float*)d_in[4];
    const float* Wk   = (const float*)d_in[5];
    const float* Wv   = (const float*)d_in[6];
    const float* Wo   = (const float*)d_in[7];
    const float* Wr   = (const float*)d_in[8];
    const float* Wg   = (const float*)d_in[9];
    float* out = (float*)d_out;
    float* hm  = out + (size_t)B_ * T_ * C_;

    const int M = B_ * T_;  // 8192
    float* ws = (float*)d_ws;
    float* qf32  = ws;                  // 8388608 f   [after rope_q: yb bf16]
    float* kf32  = qf32 + 8388608;      // 4194304 f
    float* xbr   = kf32 + 4194304;      // 4194304 f (bf16 x) [after QKV gemm: qb bf16]
    float* wqkvr = xbr + 4194304;       // 1048576 f (bf16 Wqkv)
    float* wor   = wqkvr + 1048576;     // 524288 f  (bf16 Wo)
    float* gate  = wor + 524288;        // 65536 f
    float* vtr   = gate + 65536;        // 2097152 f (bf16 vT [b][kv][d][t], from GEMM)
    float* kbr   = vtr + 2097152;       // 2097152 f (bf16 k roped, head-major)

    u16* xb    = (u16*)xbr;
    u16* Wqkvb = (u16*)wqkvr;
    u16* Wob   = (u16*)wor;
    u16* vbT   = (u16*)vtr;
    u16* qb    = (u16*)xbr;    // overlays xb (dead after QKV GEMM), head-major
    u16* kb    = (u16*)kbr;    // head-major
    u16* yb    = (u16*)qf32;   // overlays qf32 (dead after rope_q)

    // ---- weight casts ----
    cast_weights_kernel<<<3072, 256, 0, stream>>>(Wq, Wk, Wv, Wo, Wqkvb, Wob);
    // ---- router (gate feeds the fused V epilogue; also emits xb) ----
    logits_mask_gate_kernel<<<M, 64, 0, stream>>>(x, Wr, Wg, hm, gate, xb);
    // ---- fused QKV projection (256x128 counted-vmcnt pipeline; v written as vbT) ----
    gemm_bf16_256<1><<<dim3(2048 / 128, M / 256), 512, 0, stream>>>(
        xb, Wqkvb, nullptr, M, 2048, C_, qf32, kf32, vbT, gate, ve);
    // ---- rope+rms -> bf16 head-major (q folded with 1/sqrt(HD)*log2e for exp2 softmax) ----
    rope_rms_kernel<<<(M * NH_) / 16, 256, 0, stream>>>(qf32, 1024, qb, cosT, sinT, 4, 0.125f * LOG2E_);
    rope_rms_kernel<<<(M * NKV_) / 16, 256, 0, stream>>>(kf32, 512, kb, cosT, sinT, 3, 1.0f);
    // ---- flash attention (QBLK=128, 8 waves; truncating P pack) ----
    attn_mfma_kernel<<<B_ * NH_ * (T_ / 128), 512, 0, stream>>>(qb, kb, vbT, hm, yb);
    // ---- output projection (256x128 pipeline) ----
    gemm_bf16_256<0><<<dim3(C_ / 128, M / 256), 512, 0, stream>>>(
        yb, Wob, out, M, C_, C_, nullptr, nullptr, nullptr, nullptr, nullptr);
}

// Round 19
// 222.465 us; speedup vs baseline: 1.6026x; 1.2207x over previous
//
#include <hip/hip_runtime.h>
#include <math.h>

#define B_ 4
#define T_ 2048
#define C_ 1024
#define NH_ 16
#define NKV_ 8
#define HD_ 64
#define KACT_ 8
#define VG_ 32
#define EPS_ 1e-6f
#define LOG2E_ 1.44269504088896340736f

typedef __attribute__((ext_vector_type(8))) short bf16x8;
typedef __attribute__((ext_vector_type(4))) float f32x4;
typedef __attribute__((ext_vector_type(4))) unsigned short u16x4;
typedef unsigned short u16;
typedef unsigned int u32;

__device__ inline u16 f2bf(float f) {
    u32 u = __float_as_uint(f);
    u += 0x7fffu + ((u >> 16) & 1u);   // RNE (finite data)
    return (u16)(u >> 16);
}

__device__ inline u16 f2bf_t(float f) {        // truncating (P>=0 softmax weights only)
    return (u16)(__float_as_uint(f) >> 16);
}

__device__ inline float fast_exp2(float x) {   // bare v_exp_f32 (D = 2^S0), no libm guards
    float r;
    asm("v_exp_f32 %0, %1" : "=v"(r) : "v"(x));
    return r;
}

__device__ inline void gload_lds16(const void* g, void* s) {
    __builtin_amdgcn_global_load_lds((const __attribute__((address_space(1))) void*)g,
                                     (__attribute__((address_space(3))) void*)s, 16, 0, 0);
}

__device__ inline void bar() {                 // raw barrier + compiler memory fence
    asm volatile("" ::: "memory");
    __builtin_amdgcn_s_barrier();
    asm volatile("" ::: "memory");
}

// st_16x32 swizzle (involution): byte ^= ((byte>>9)&1)<<5 within a 16KB [128][64]bf16 unit
__device__ inline int swz(int b) { return b ^ (((b >> 9) & 1) << 5); }

// ===================== fused weight casts: Wq|Wk|Wv -> wqkv, Wo -> wo =====================
__global__ __launch_bounds__(256) void cast_weights_kernel(
    const float* __restrict__ Wq, const float* __restrict__ Wk,
    const float* __restrict__ Wv, const float* __restrict__ Wo,
    u16* __restrict__ wqkv, u16* __restrict__ wo)
{
    int i = blockIdx.x * 256 + threadIdx.x;    // 786432 float4 chunks total
    const float* src; u16* dst; int j;
    if (i < 262144)      { src = Wq; dst = wqkv;           j = i; }
    else if (i < 393216) { src = Wk; dst = wqkv + 1048576; j = i - 262144; }
    else if (i < 524288) { src = Wv; dst = wqkv + 1572864; j = i - 393216; }
    else                 { src = Wo; dst = wo;             j = i - 524288; }
    float4 v = ((const float4*)src)[j];
    u16x4 o = { f2bf(v.x), f2bf(v.y), f2bf(v.z), f2bf(v.w) };
    ((u16x4*)dst)[j] = o;
}

// ===================== bf16 NT-GEMM: 256x128 tile, counted-vmcnt pipeline (R16-proven) ==
// Out = A(MxK) * W(NxK)^T. BK=64, 512 threads = 8 waves (2M x 4N), wave tile 128x32.
// A triple-buffered (stage kt+2), B double-buffered (stage kt+1). vmcnt(4) at K-tile
// entry; vmcnt(0) only at the last K-tile. st_16x32 swizzle as involution on source
// chunk + read byte. K order identical to R2 kernel -> bit-identical accumulators.
// MODE 0: plain f32 Out. MODE 1: fused QKV epilogue:
//   q f32 token-major; k f32 token-major; v -> gate*ve add, bf16, written DIRECTLY
//   transposed as vbT[b][kv][d][t] (4 consecutive tokens per thread = packed 8B store).
template<int MODE>
__global__ __launch_bounds__(512) void gemm_bf16_256(
    const u16* __restrict__ A, const u16* __restrict__ W,
    float* __restrict__ Out, int M, int N, int K,
    float* __restrict__ q_out, float* __restrict__ k_out, u16* __restrict__ vT_out,
    const float* __restrict__ gate, const float* __restrict__ ve)
{
    __shared__ __align__(16) u16 AL[3][2][128 * 64];   // 96 KB
    __shared__ __align__(16) u16 BL[2][128 * 64];      // 32 KB
    const int tid = threadIdx.x;
    const int lane = tid & 63;
    const int w = tid >> 6;
    const int bm = blockIdx.y * 256;
    const int bn = blockIdx.x * 128;
    const int wm = (w >> 2) * 128;     // A half = w>>2
    const int wn = (w & 3) * 32;
    const int ah = w >> 2;
    const int lr = lane & 15, lg = lane >> 4;
    const int NKT = K >> 6;            // 16

    f32x4 acc[8][2];
    #pragma unroll
    for (int mi = 0; mi < 8; ++mi)
        #pragma unroll
        for (int ni = 0; ni < 2; ++ni) acc[mi][ni] = f32x4{0.f, 0.f, 0.f, 0.f};

    auto stageA = [&](int kt) {        // both halves, 4 loads FIFO
        const int db = kt % 3;
        #pragma unroll
        for (int hf = 0; hf < 2; ++hf)
            #pragma unroll
            for (int ci = 0; ci < 2; ++ci) {
                int c = tid + ci * 512;
                int l = c ^ (((c >> 5) & 1) << 1);
                gload_lds16(A + (size_t)(bm + hf * 128 + (l >> 3)) * K + kt * 64 + (l & 7) * 8,
                            (char*)&AL[db][hf][0] + c * 16);
            }
    };
    auto stageB = [&](int kt) {        // 2 loads
        const int db = kt & 1;
        #pragma unroll
        for (int ci = 0; ci < 2; ++ci) {
            int c = tid + ci * 512;
            int l = c ^ (((c >> 5) & 1) << 1);
            gload_lds16(W + (size_t)(bn + (l >> 3)) * K + kt * 64 + (l & 7) * 8,
                        (char*)&BL[db][0] + c * 16);
        }
    };

    stageA(0);
    stageB(0);
    stageA(1);                          // FIFO: [A0(4), B0(2), A1(4)]

    for (int kt = 0; kt < NKT; ++kt) {
        const int ab = kt % 3, bb = kt & 1;
        if (kt == NKT - 1) asm volatile("s_waitcnt vmcnt(0)" ::: "memory");
        else               asm volatile("s_waitcnt vmcnt(4)" ::: "memory");
        bar();                          // all waves' loads for K-tile kt landed
        #pragma unroll
        for (int ph = 0; ph < 2; ++ph) {
            bf16x8 af[4][2], bfm[2][2];
            #pragma unroll
            for (int mi2 = 0; mi2 < 4; ++mi2) {
                const int row = (ph * 4 + mi2) * 16 + lr;
                #pragma unroll
                for (int kk = 0; kk < 2; ++kk)
                    af[mi2][kk] = *(const bf16x8*)((const char*)&AL[ab][ah][0] +
                                                   swz(row * 128 + kk * 64 + lg * 16));
            }
            #pragma unroll
            for (int ni = 0; ni < 2; ++ni) {
                const int row = wn + ni * 16 + lr;
                #pragma unroll
                for (int kk = 0; kk < 2; ++kk)
                    bfm[ni][kk] = *(const bf16x8*)((const char*)&BL[bb][0] +
                                                   swz(row * 128 + kk * 64 + lg * 16));
            }
            if (ph == 0) { if (kt + 1 < NKT) stageB(kt + 1); }
            else         { if (kt + 2 < NKT) stageA(kt + 2); }
            bar();
            __builtin_amdgcn_s_setprio(1);
            #pragma unroll
            for (int mi2 = 0; mi2 < 4; ++mi2)
                #pragma unroll
                for (int ni = 0; ni < 2; ++ni)
                    #pragma unroll
                    for (int kk = 0; kk < 2; ++kk)
                        acc[ph * 4 + mi2][ni] = __builtin_amdgcn_mfma_f32_16x16x32_bf16(
                            af[mi2][kk], bfm[ni][kk], acc[ph * 4 + mi2][ni], 0, 0, 0);
            __builtin_amdgcn_s_setprio(0);
            bar();
        }
    }

    #pragma unroll
    for (int mi = 0; mi < 8; ++mi)
        #pragma unroll
        for (int ni = 0; ni < 2; ++ni) {
            const int row0 = bm + wm + mi * 16 + lg * 4;   // 4 consecutive tokens, same b
            const int col = bn + wn + ni * 16 + lr;
            if (MODE == 0) {
                #pragma unroll
                for (int r = 0; r < 4; ++r)
                    Out[(size_t)(row0 + r) * N + col] = acc[mi][ni][r];
            } else {
                if (col < 1024) {
                    #pragma unroll
                    for (int r = 0; r < 4; ++r)
                        q_out[(size_t)(row0 + r) * 1024 + col] = acc[mi][ni][r];
                } else if (col < 1536) {
                    #pragma unroll
                    for (int r = 0; r < 4; ++r)
                        k_out[(size_t)(row0 + r) * 512 + (col - 1024)] = acc[mi][ni][r];
                } else {
                    const int cc = col - 1536;
                    const int kv = cc >> 6, d = cc & 63;
                    u16x4 pk;
                    #pragma unroll
                    for (int r = 0; r < 4; ++r) {
                        const int row = row0 + r;
                        pk[r] = f2bf(acc[mi][ni][r] +
                                     gate[row * NKV_ + kv] * ve[(size_t)row * 512 + cc]);
                    }
                    *(u16x4*)(vT_out + ((size_t)((row0 >> 11) * NKV_ + kv) * HD_ + d) * T_ +
                              (row0 & (T_ - 1))) = pk;
                }
            }
        }
}

// ===================== Router + top-8 mask + gate + fused x->bf16 cast (R12-proven) ====
__global__ __launch_bounds__(64) void logits_mask_gate_kernel(
    const float* __restrict__ x, const float* __restrict__ Wr,
    const float* __restrict__ Wg, float* __restrict__ hm, float* __restrict__ gate,
    u16* __restrict__ xb)
{
    const int token = blockIdx.x;
    const int lane = threadIdx.x;
    const float* xr = x + (size_t)token * C_;
    __shared__ float lg[NH_];
    __shared__ float thr_s;
    float part[NH_];
    #pragma unroll
    for (int h = 0; h < NH_; ++h) part[h] = 0.f;
    for (int c = lane; c < C_; c += 64) {
        float xv = xr[c];
        xb[(size_t)token * C_ + c] = f2bf(xv);   // fused cast
        #pragma unroll
        for (int h = 0; h < NH_; ++h) part[h] = fmaf(xv, Wr[h * C_ + c], part[h]);
    }
    #pragma unroll
    for (int h = 0; h < NH_; ++h) {
        float s = part[h];
        #pragma unroll
        for (int off = 32; off; off >>= 1) s += __shfl_xor(s, off);
        if (lane == 0) lg[h] = s;
    }
    __syncthreads();
    if (lane == 0) {
        unsigned used = 0;
        float last = 0.f;
        for (int p = 0; p < KACT_; ++p) {
            float bv = -3.4e38f; int bi = 0;
            for (int i = 0; i < NH_; ++i)
                if (!(used & (1u << i)) && lg[i] > bv) { bv = lg[i]; bi = i; }
            used |= 1u << bi;
            last = bv;
        }
        thr_s = last;
    }
    __syncthreads();
    if (lane < NH_) hm[(size_t)token * NH_ + lane] = (lg[lane] >= thr_s) ? 1.f : 0.f;
    if (lane < NKV_) {
        float s = 0.f;
        #pragma unroll
        for (int g = 0; g < VG_; ++g) s = fmaf(xr[g], Wg[lane * VG_ + g], s);
        gate[(size_t)token * NKV_ + lane] = 2.f / (1.f + __expf(-s));
    }
}

// ===================== rotary + rms-norm, 16-vec/block, HEAD-major out (R7-proven) ====
__global__ __launch_bounds__(256) void rope_rms_kernel(
    const float* __restrict__ src, int src_stride, u16* __restrict__ dst,
    const float* __restrict__ cosT, const float* __restrict__ sinT,
    int hshift, float scale)
{
    const int tid = threadIdx.x;
    const int vec = blockIdx.x * 16 + (tid >> 4);   // = m*heads + h
    const int idx = tid & 15;
    const int heads = 1 << hshift;
    const int m = vec >> hshift;
    const int hh = vec & (heads - 1);
    const int t = m & (T_ - 1);
    const int bb = m >> 11;
    const float4 v4 = *(const float4*)(src + (size_t)m * src_stride + hh * 64 + idx * 4);
    const float4 c4 = *(const float4*)(cosT + t * 32 + (idx & 7) * 4);
    const float4 s4 = *(const float4*)(sinT + t * 32 + (idx & 7) * 4);
    const float p0 = __shfl_xor(v4.x, 8);
    const float p1 = __shfl_xor(v4.y, 8);
    const float p2 = __shfl_xor(v4.z, 8);
    const float p3 = __shfl_xor(v4.w, 8);
    float r0, r1, r2, r3;
    if (idx < 8) {
        r0 = fmaf(v4.x, c4.x, p0 * s4.x); r1 = fmaf(v4.y, c4.y, p1 * s4.y);
        r2 = fmaf(v4.z, c4.z, p2 * s4.z); r3 = fmaf(v4.w, c4.w, p3 * s4.w);
    } else {
        r0 = fmaf(v4.x, c4.x, -p0 * s4.x); r1 = fmaf(v4.y, c4.y, -p1 * s4.y);
        r2 = fmaf(v4.z, c4.z, -p2 * s4.z); r3 = fmaf(v4.w, c4.w, -p3 * s4.w);
    }
    float ss = fmaf(r0, r0, fmaf(r1, r1, fmaf(r2, r2, r3 * r3)));
    ss += __shfl_xor(ss, 1);
    ss += __shfl_xor(ss, 2);
    ss += __shfl_xor(ss, 4);
    ss += __shfl_xor(ss, 8);
    const float sc = rsqrtf(ss * (1.0f / HD_) + EPS_) * scale;
    u16x4 o = { f2bf(r0 * sc), f2bf(r1 * sc), f2bf(r2 * sc), f2bf(r3 * sc) };
    *(u16x4*)(dst + ((size_t)(bb * heads + hh) * T_ + t) * HD_ + idx * 4) = o;
}

// ===================== MFMA flash attention v7: balanced grid (qblk in HIGH bits) =====
// bid = (15-qblk)*64 + b*16 + h. Under stride-256 CU aliasing each CU hosts 4 blocks
// with qblk spread {15-j,11-j,7-j,3-j} -> per-CU work 56..80 tile-units (was 128 vs 8,
// a 16:1 imbalance with qblk in the low bits). Longest classes still dispatch first.
// Per-tile math R12-lineage (elementwise mask; branchy form BANNED: R9/R10). LDS
// staging REQUIRED (R13). Truncating P pack (R18-proven).
__global__ __launch_bounds__(512) void attn_mfma_kernel(
    const u16* __restrict__ qb, const u16* __restrict__ kb,
    const u16* __restrict__ vbT, const float* __restrict__ hm,
    u16* __restrict__ yb)
{
    __shared__ __align__(16) u16 Ks[64 * 72];
    __shared__ __align__(16) u16 Vt[64 * 72];
    __shared__ __align__(16) u16 Ps[8 * 16 * 72];
    const int bid = blockIdx.x;
    const int qblk = 15 - (bid >> 6);          // HIGH bits; reversed: longest first
    const int b = (bid >> 4) & 3;
    const int h = bid & 15;
    const int kv = h >> 1;
    const int tid = threadIdx.x;
    const int lane = tid & 63;
    const int w = tid >> 6;                    // 0..7
    const int lr = lane & 15;
    const int lg = lane >> 4;
    const int q0 = qblk * 128;
    const int qt_max = 2 * qblk + 1;

    bf16x8 qf[2];
    {
        const u16* src = qb + ((size_t)(b * NH_ + h) * T_ + q0 + w * 16 + lr) * HD_ + lg * 8;
        qf[0] = *(const bf16x8*)(src);
        qf[1] = *(const bf16x8*)(src + 32);
    }
    f32x4 yacc[4];
    #pragma unroll
    for (int dt = 0; dt < 4; ++dt) yacc[dt] = f32x4{0.f, 0.f, 0.f, 0.f};
    float m = -1e30f, l = 0.f;

    const u16* kbase = kb + (size_t)(b * NKV_ + kv) * T_ * HD_;            // head-major [t][64]
    const u16* vbase = vbT + ((size_t)(b * NKV_) + kv) * (size_t)HD_ * T_; // [d][t]
    u16* Pw = Ps + w * 16 * 72;
    const int qrow_g = q0 + w * 16 + lr;

    const int a0 = tid >> 3, g0 = tid & 7;
    bf16x8 kreg, vreg;
    auto LOADT = [&](int kt) {
        kreg = *(const bf16x8*)(kbase + (size_t)(kt * 64 + a0) * HD_ + g0 * 8);
        vreg = *(const bf16x8*)(vbase + (size_t)a0 * T_ + kt * 64 + g0 * 8);
    };
    auto WRITET = [&]() {
        *(bf16x8*)&Ks[a0 * 72 + g0 * 8] = kreg;
        *(bf16x8*)&Vt[a0 * 72 + g0 * 8] = vreg;
    };

    LOADT(0);
    WRITET();
    for (int kt = 0; kt <= qt_max; ++kt) {
        __syncthreads();                       // tile kt visible in LDS
        if (kt < qt_max) LOADT(kt + 1);        // prefetch next tile into regs
        const int rel = q0 + w * 16 + 15 - kt * 64;
        if (rel >= 0) {                        // wave-uniform skip of fully-masked tiles
            const int mtmax = min(3, rel >> 4);
            f32x4 st[4];
            #pragma unroll
            for (int mt = 0; mt < 4; ++mt) st[mt] = f32x4{0.f, 0.f, 0.f, 0.f};
            __builtin_amdgcn_s_setprio(1);
            #pragma unroll
            for (int mt = 0; mt < 4; ++mt) {
                if (mt <= mtmax) {
                    bf16x8 kf0 = *(const bf16x8*)&Ks[(mt * 16 + lr) * 72 + lg * 8];
                    bf16x8 kf1 = *(const bf16x8*)&Ks[(mt * 16 + lr) * 72 + lg * 8 + 32];
                    st[mt] = __builtin_amdgcn_mfma_f32_16x16x32_bf16(kf0, qf[0], st[mt], 0, 0, 0);
                    st[mt] = __builtin_amdgcn_mfma_f32_16x16x32_bf16(kf1, qf[1], st[mt], 0, 0, 0);
                }
            }
            __builtin_amdgcn_s_setprio(0);
            // mask + per-q max (elementwise PROVEN form)
            float smax = -1e30f;
            #pragma unroll
            for (int mt = 0; mt < 4; ++mt) {
                #pragma unroll
                for (int r = 0; r < 4; ++r) {
                    int keyg = kt * 64 + mt * 16 + lg * 4 + r;
                    float s = (mt <= mtmax && keyg <= qrow_g) ? st[mt][r] : -1e30f;
                    st[mt][r] = s;
                    smax = fmaxf(smax, s);
                }
            }
            smax = fmaxf(smax, __shfl_xor(smax, 16));
            smax = fmaxf(smax, __shfl_xor(smax, 32));
            if (!__all(smax <= m + 8.f)) {     // defer-max: P bounded by 2^8, bf16-safe
                const float mnew = fmaxf(m, smax);
                const float corr = fast_exp2(m - mnew);
                l *= corr;
                float cr[4];
                #pragma unroll
                for (int r = 0; r < 4; ++r) cr[r] = __shfl(corr, lg * 4 + r);
                #pragma unroll
                for (int dt = 0; dt < 4; ++dt)
                    #pragma unroll
                    for (int r = 0; r < 4; ++r) yacc[dt][r] *= cr[r];
                m = mnew;
            }
            float psum = 0.f;
            #pragma unroll
            for (int mt = 0; mt < 4; ++mt) {
                float p0 = fast_exp2(st[mt][0] - m);
                float p1 = fast_exp2(st[mt][1] - m);
                float p2 = fast_exp2(st[mt][2] - m);
                float p3 = fast_exp2(st[mt][3] - m);
                psum += (p0 + p1) + (p2 + p3);
                u16x4 pk = { f2bf_t(p0), f2bf_t(p1), f2bf_t(p2), f2bf_t(p3) };
                *(u16x4*)&Pw[lr * 72 + mt * 16 + lg * 4] = pk;
            }
            psum += __shfl_xor(psum, 16);
            psum += __shfl_xor(psum, 32);
            l += psum;
            // PV: Y[q][d] += P[q][s] * V[s][d]
            const int kimax = min(1, rel >> 5);
            __builtin_amdgcn_s_setprio(1);
            #pragma unroll
            for (int ki = 0; ki < 2; ++ki) {
                if (ki <= kimax) {
                    bf16x8 pf = *(const bf16x8*)&Pw[lr * 72 + ki * 32 + lg * 8];
                    #pragma unroll
                    for (int dt = 0; dt < 4; ++dt) {
                        bf16x8 vf = *(const bf16x8*)&Vt[(dt * 16 + lr) * 72 + ki * 32 + lg * 8];
                        yacc[dt] = __builtin_amdgcn_mfma_f32_16x16x32_bf16(pf, vf, yacc[dt], 0, 0, 0);
                    }
                }
            }
            __builtin_amdgcn_s_setprio(0);
        }
        __syncthreads();                       // all waves done reading tile kt
        if (kt < qt_max) WRITET();             // overwrite LDS with tile kt+1
    }
    const float linv = 1.f / l;
    #pragma unroll
    for (int r = 0; r < 4; ++r) {
        const float lrv = __shfl(linv, lg * 4 + r);
        const int t = q0 + w * 16 + lg * 4 + r;
        const float hmv = hm[((size_t)(b * T_) + t) * NH_ + h];
        const float sc = lrv * hmv;
        #pragma unroll
        for (int dt = 0; dt < 4; ++dt)
            yb[(((size_t)(b * T_) + t) * NH_ + h) * HD_ + dt * 16 + lr] = f2bf(yacc[dt][r] * sc);
    }
}

extern "C" void kernel_launch(void* const* d_in, const int* in_sizes, int n_in,
                              void* d_out, int out_size, void* d_ws, size_t ws_size,
                              hipStream_t stream) {
    const float* x    = (const float*)d_in[0];
    const float* ve   = (const float*)d_in[1];
    const float* cosT = (const float*)d_in[2];
    const float* sinT = (const float*)d_in[3];
    const float* Wq   = (const float*)d_in[4];
    const float* Wk   = (const float*)d_in[5];
    const float* Wv   = (const float*)d_in[6];
    const float* Wo   = (const float*)d_in[7];
    const float* Wr   = (const float*)d_in[8];
    const float* Wg   = (const float*)d_in[9];
    float* out = (float*)d_out;
    float* hm  = out + (size_t)B_ * T_ * C_;

    const int M = B_ * T_;  // 8192
    float* ws = (float*)d_ws;
    float* qf32  = ws;                  // 8388608 f   [after rope_q: yb bf16]
    float* kf32  = qf32 + 8388608;      // 4194304 f
    float* xbr   = kf32 + 4194304;      // 4194304 f (bf16 x) [after QKV gemm: qb bf16]
    float* wqkvr = xbr + 4194304;       // 1048576 f (bf16 Wqkv)
    float* wor   = wqkvr + 1048576;     // 524288 f  (bf16 Wo)
    float* gate  = wor + 524288;        // 65536 f
    float* vtr   = gate + 65536;        // 2097152 f (bf16 vT [b][kv][d][t], from GEMM)
    float* kbr   = vtr + 2097152;       // 2097152 f (bf16 k roped, head-major)

    u16* xb    = (u16*)xbr;
    u16* Wqkvb = (u16*)wqkvr;
    u16* Wob   = (u16*)wor;
    u16* vbT   = (u16*)vtr;
    u16* qb    = (u16*)xbr;    // overlays xb (dead after QKV GEMM), head-major
    u16* kb    = (u16*)kbr;    // head-major
    u16* yb    = (u16*)qf32;   // overlays qf32 (dead after rope_q)

    // ---- weight casts ----
    cast_weights_kernel<<<3072, 256, 0, stream>>>(Wq, Wk, Wv, Wo, Wqkvb, Wob);
    // ---- router (gate feeds the fused V epilogue; also emits xb) ----
    logits_mask_gate_kernel<<<M, 64, 0, stream>>>(x, Wr, Wg, hm, gate, xb);
    // ---- fused QKV projection (256x128 counted-vmcnt pipeline; v written as vbT) ----
    gemm_bf16_256<1><<<dim3(2048 / 128, M / 256), 512, 0, stream>>>(
        xb, Wqkvb, nullptr, M, 2048, C_, qf32, kf32, vbT, gate, ve);
    // ---- rope+rms -> bf16 head-major (q folded with 1/sqrt(HD)*log2e for exp2 softmax) ----
    rope_rms_kernel<<<(M * NH_) / 16, 256, 0, stream>>>(qf32, 1024, qb, cosT, sinT, 4, 0.125f * LOG2E_);
    rope_rms_kernel<<<(M * NKV_) / 16, 256, 0, stream>>>(kf32, 512, kb, cosT, sinT, 3, 1.0f);
    // ---- flash attention (QBLK=128, 8 waves; balanced grid) ----
    attn_mfma_kernel<<<B_ * NH_ * (T_ / 128), 512, 0, stream>>>(qb, kb, vbT, hm, yb);
    // ---- output projection (256x128 pipeline) ----
    gemm_bf16_256<0><<<dim3(C_ / 128, M / 256), 512, 0, stream>>>(
        yb, Wob, out, M, C_, C_, nullptr, nullptr, nullptr, nullptr, nullptr);
}